// Round 5
// baseline (3214.668 us; speedup 1.0000x reference)
//
#include <hip/hip_runtime.h>
#include <hip/hip_bf16.h>
#include <cstddef>

typedef __hip_bfloat16 bf16;
typedef __attribute__((ext_vector_type(8))) short short8;
typedef __attribute__((ext_vector_type(4))) float float4v;
typedef __attribute__((ext_vector_type(4))) unsigned short ushort4v;

static __device__ __forceinline__ float b2f(bf16 v) { return __bfloat162float(v); }
static __device__ __forceinline__ float bits2f(unsigned int u) { return __uint_as_float(u); }
static __device__ __forceinline__ unsigned short f2bfbits(float f) {
  bf16 h = __float2bfloat16(f);
  return *reinterpret_cast<unsigned short*>(&h);
}
static __device__ __forceinline__ float ld_any(const void* p, long i, int flag) {
  return flag ? b2f(((const bf16*)p)[i]) : ((const float*)p)[i];
}
static __device__ __forceinline__ void unpack_u4(uint4 u, float* f) {
  f[0] = bits2f(u.x << 16); f[1] = bits2f(u.x & 0xffff0000u);
  f[2] = bits2f(u.y << 16); f[3] = bits2f(u.y & 0xffff0000u);
  f[4] = bits2f(u.z << 16); f[5] = bits2f(u.z & 0xffff0000u);
  f[6] = bits2f(u.w << 16); f[7] = bits2f(u.w & 0xffff0000u);
}

// --------------------------------------------------------- dtype detection
__global__ void detect_dtype_kernel(const void* __restrict__ x, int* __restrict__ flag) {
  __shared__ int ok;
  if (threadIdx.x == 0) ok = 1;
  __syncthreads();
  float v = b2f(((const bf16*)x)[threadIdx.x]);
  if (!(v >= 0.f && v <= 1.0009765625f)) ok = 0;
  __syncthreads();
  if (threadIdx.x == 0) *flag = ok;
}

// ---------------------------------------------------------------- utilities
__global__ void zero_kernel(uint4* __restrict__ p, long n4) {
  long i = (long)blockIdx.x * blockDim.x + threadIdx.x;
  long stride = (long)gridDim.x * blockDim.x;
  uint4 z = {0u, 0u, 0u, 0u};
  for (; i < n4; i += stride) p[i] = z;
}
__global__ void zero2_kernel(float* p) {
  if (threadIdx.x < 2) p[threadIdx.x] = 0.f;
}
__global__ void conv_f32(const void* __restrict__ src, float* __restrict__ dst,
                         int n, const int* __restrict__ flag) {
  int i = blockIdx.x * blockDim.x + threadIdx.x;
  if (i < n) dst[i] = ld_any(src, i, *flag);
}
__global__ void conv_bf16(const void* __restrict__ src, bf16* __restrict__ dst,
                          int n, const int* __restrict__ flag) {
  int i = blockIdx.x * blockDim.x + threadIdx.x;
  if (i >= n) return;
  dst[i] = (*flag) ? ((const bf16*)src)[i] : __float2bfloat16(((const float*)src)[i]);
}
__global__ void embsq_kernel(const bf16* __restrict__ emb, float* __restrict__ out) {
  int k = blockIdx.x * blockDim.x + threadIdx.x;
  if (k >= 512) return;
  float s = 0.f;
  for (int c = 0; c < 128; ++c) { float e = b2f(emb[k * 128 + c]); s = fmaf(e, e, s); }
  out[k] = s;
}

// conv1 weights [64][3][4][4] -> [tap=ci*16+k][co] fp32
__global__ void rp_conv1_w(const void* __restrict__ src, float* __restrict__ dst,
                           const int* __restrict__ flag) {
  int i = blockIdx.x * blockDim.x + threadIdx.x;
  if (i >= 3072) return;
  int co = i / 48, rem = i % 48;
  dst[rem * 64 + co] = ld_any(src, i, *flag);
}

// weights OIHW [CO][CI][4][4] -> [tap=kh*4+kw][co][ci] bf16
template <int CO, int CI>
__global__ void rp_conv_w(const void* __restrict__ src, bf16* __restrict__ dst,
                          const int* __restrict__ flag) {
  const int N = CO * CI * 16;
  int i = blockIdx.x * blockDim.x + threadIdx.x;
  if (i >= N) return;
  int co = i / (CI * 16);
  int rem = i % (CI * 16);
  int ci = rem >> 4;
  int k = rem & 15;
  dst[((long)k * CO + co) * CI + ci] = __float2bfloat16(ld_any(src, i, *flag));
}

// convT weights [CI][CO][4][4] -> [class pq][tap st][co][ci] bf16
template <int CI, int CO>
__global__ void rp_convt_w(const void* __restrict__ src, bf16* __restrict__ dst,
                           const int* __restrict__ flag) {
  const int N = CI * CO * 16;
  int i = blockIdx.x * blockDim.x + threadIdx.x;
  if (i >= N) return;
  int ci = i / (CO * 16);
  int rem = i % (CO * 16);
  int co = rem >> 4;
  int k = rem & 15;
  int kh = k >> 2, kw = k & 3;
  int p = (kh + 1) & 1, s = (kh - 1 + p) >> 1;
  int q = (kw + 1) & 1, t = (kw - 1 + q) >> 1;
  long d = (((long)(p * 2 + q) * 4 + (s * 2 + t)) * CO + co) * CI + ci;
  dst[d] = __float2bfloat16(ld_any(src, i, *flag));
}

// ------------------- conv1: 3->64 s2, one thread per position, 64 co each
__global__ __launch_bounds__(256) void conv1_nhwc_v2(const void* __restrict__ x,
                                                     const int* __restrict__ flag,
                                                     const float* __restrict__ wt,
                                                     const float* __restrict__ bf_,
                                                     bf16* __restrict__ act1p) {
  __shared__ float wl[48 * 64];
  for (int i = threadIdx.x; i < 3072; i += 256) wl[i] = wt[i];
  __syncthreads();
  int tid = blockIdx.x * 256 + threadIdx.x;   // 16*128*128 total
  int ow = tid & 127; int t = tid >> 7;
  int oh = t & 127; int b = t >> 7;
  int fl = *flag;
  float4v acc[16];
  #pragma unroll
  for (int j = 0; j < 16; ++j) acc[j] = *(const float4v*)(bf_ + j * 4);
  int ih0 = oh * 2 - 1, iw0 = ow * 2 - 1;
  #pragma unroll
  for (int ci = 0; ci < 3; ++ci) {
    long pbase = ((long)(b * 3 + ci)) * 65536;
    #pragma unroll
    for (int kh = 0; kh < 4; ++kh) {
      int ih = ih0 + kh;
      bool okh = (unsigned)ih < 256u;
      long rbase = pbase + (long)ih * 256;
      #pragma unroll
      for (int kw = 0; kw < 4; ++kw) {
        int iw = iw0 + kw;
        float xv = (okh && (unsigned)iw < 256u) ? ld_any(x, rbase + iw, fl) : 0.f;
        const float* wrow = wl + (ci * 16 + kh * 4 + kw) * 64;
        #pragma unroll
        for (int j = 0; j < 16; ++j) {
          float4v wv = *(const float4v*)(wrow + j * 4);
          #pragma unroll
          for (int e = 0; e < 4; ++e) acc[j][e] = fmaf(xv, wv[e], acc[j][e]);
        }
      }
    }
  }
  bf16* orow = act1p + ((long)(b * 130 + oh + 1) * 130 + ow + 1) * 64;
  #pragma unroll
  for (int j = 0; j < 16; ++j) {
    ushort4v o;
    #pragma unroll
    for (int e = 0; e < 4; ++e) o[e] = f2bfbits(fmaxf(acc[j][e], 0.f));
    *(ushort4v*)(orow + j * 4) = o;
  }
}

// ------------------------------------------- MFMA implicit-GEMM tap conv
template <int COUT, int CINT, int TC, int S, int NT, int INC>
__global__ __launch_bounds__(256) void mfma_conv(
    const bf16* __restrict__ in1, const bf16* __restrict__ in2,
    long inImgS, int inRowS,
    const bf16* __restrict__ w, const float* __restrict__ bias,
    bf16* __restrict__ outp, long outImgS, int oRS, int oCS, int pq) {
  constexpr int TR = 128 / TC;
  constexpr int KC = CINT / 32;
  constexpr int KSPLIT = (CINT > INC) ? (INC / 32) : KC;
  const int lane = threadIdx.x & 63;
  const int wv = threadIdx.x >> 6;
  const int wm = wv & 1, wn = wv >> 1;
  const int ln = lane & 15, quad = lane >> 4;
  const int mTile = blockIdx.y * 64;
  const int oh0 = blockIdx.x * TR;
  const int b = blockIdx.z;
  const int p = pq >> 1, q = pq & 1;

  long posOff[4];
  int rr[4], cc[4];
  #pragma unroll
  for (int bf = 0; bf < 4; ++bf) {
    int n = wn * 64 + bf * 16 + ln;
    int r = n / TC, c = n % TC;
    rr[bf] = r; cc[bf] = c;
    posOff[bf] = (long)(S * (oh0 + r)) * inRowS + (long)(S * c) * INC;
  }
  const bf16* inb1 = in1 + (long)b * inImgS;
  const bf16* inb2 = in2 + (long)b * inImgS;

  float4v acc[2][4];
  #pragma unroll
  for (int i = 0; i < 2; ++i)
    #pragma unroll
    for (int j = 0; j < 4; ++j) acc[i][j] = {0.f, 0.f, 0.f, 0.f};

  for (int t = 0; t < NT; ++t) {
    int dy, dx;
    if (S == 2) { dy = t >> 2; dx = t & 3; }
    else        { dy = p - (t >> 1) + 1; dx = q - (t & 1) + 1; }
    const long tapOff = (long)dy * inRowS + (long)dx * INC;
    const bf16* wt = w + (long)t * COUT * CINT;
    const bf16* wk0 = wt + (long)(mTile + wm * 32 + ln) * CINT + quad * 8;
    #pragma unroll
    for (int kc = 0; kc < KC; ++kc) {
      short8 a0 = *(const short8*)(wk0 + kc * 32);
      short8 a1 = *(const short8*)(wk0 + kc * 32 + 16 * CINT);
      const bf16* bp = (kc < KSPLIT) ? inb1 : inb2;
      int kOff = (kc < KSPLIT ? kc : kc - KSPLIT) * 32 + quad * 8;
      #pragma unroll
      for (int bf = 0; bf < 4; ++bf) {
        short8 bv = *(const short8*)(bp + posOff[bf] + tapOff + kOff);
        acc[0][bf] = __builtin_amdgcn_mfma_f32_16x16x32_bf16(a0, bv, acc[0][bf], 0, 0, 0);
        acc[1][bf] = __builtin_amdgcn_mfma_f32_16x16x32_bf16(a1, bv, acc[1][bf], 0, 0, 0);
      }
    }
  }

  bf16* outb = outp + (long)b * outImgS;
  #pragma unroll
  for (int mf = 0; mf < 2; ++mf) {
    int coB = mTile + wm * 32 + mf * 16 + quad * 4;
    float4v bv4 = *(const float4v*)(bias + coB);
    #pragma unroll
    for (int bf = 0; bf < 4; ++bf) {
      float4v v = acc[mf][bf];
      ushort4v o;
      #pragma unroll
      for (int e = 0; e < 4; ++e)
        o[e] = f2bfbits(fmaxf(v[e] + bv4[e], 0.f));
      long oaddr = (long)(oh0 + rr[bf]) * oRS + (long)cc[bf] * oCS + coB;
      *(ushort4v*)(outb + oaddr) = o;
    }
  }
}

// ------------------------------------------------------------- VQ quantize
__global__ __launch_bounds__(256) void vq_nhwc(
    const bf16* __restrict__ z, long zImgS, int zRowS,
    const bf16* __restrict__ emb, const float* __restrict__ embsq,
    bf16* __restrict__ zq, long qImgS, int qRowS,
    float* __restrict__ loss_acc, int HW, int Wv) {
  __shared__ float se[64 * 128];
  __shared__ float ssq[64];
  const int n = blockIdx.x * 256 + threadIdx.x;
  const int b = n / HW, rem = n % HW;
  const int y = rem / Wv, xx = rem % Wv;
  const bf16* zrow = z + (long)b * zImgS + (long)y * zRowS + (long)xx * 128;
  float zp[128];
  {
    const uint4* zr4 = (const uint4*)zrow;
    #pragma unroll
    for (int j = 0; j < 16; ++j) unpack_u4(zr4[j], zp + j * 8);
  }
  float best = 3.4e38f; int bestk = 0;
  for (int k0 = 0; k0 < 512; k0 += 64) {
    __syncthreads();
    #pragma unroll
    for (int tt = 0; tt < 32; ++tt) {
      int idx = tt * 256 + threadIdx.x;
      se[idx] = b2f(emb[(long)k0 * 128 + idx]);
    }
    if (threadIdx.x < 64) ssq[threadIdx.x] = embsq[k0 + threadIdx.x];
    __syncthreads();
    for (int kk = 0; kk < 64; kk += 4) {
      float d0 = 0.f, d1 = 0.f, d2 = 0.f, d3 = 0.f;
      const float* e0 = se + kk * 128;
      #pragma unroll
      for (int c = 0; c < 128; ++c) {
        float zc = zp[c];
        d0 = fmaf(zc, e0[c], d0);
        d1 = fmaf(zc, e0[128 + c], d1);
        d2 = fmaf(zc, e0[256 + c], d2);
        d3 = fmaf(zc, e0[384 + c], d3);
      }
      float s0 = fmaf(-2.f, d0, ssq[kk + 0]);
      float s1 = fmaf(-2.f, d1, ssq[kk + 1]);
      float s2 = fmaf(-2.f, d2, ssq[kk + 2]);
      float s3 = fmaf(-2.f, d3, ssq[kk + 3]);
      if (s0 < best) { best = s0; bestk = k0 + kk + 0; }
      if (s1 < best) { best = s1; bestk = k0 + kk + 1; }
      if (s2 < best) { best = s2; bestk = k0 + kk + 2; }
      if (s3 < best) { best = s3; bestk = k0 + kk + 3; }
    }
  }
  const uint4* er = (const uint4*)(emb + (long)bestk * 128);
  uint4* qrow = (uint4*)(zq + (long)b * qImgS + (long)y * qRowS + (long)xx * 128);
  float lsum = 0.f;
  #pragma unroll
  for (int j = 0; j < 16; ++j) {
    uint4 u = er[j];
    qrow[j] = u;
    float ev[8];
    unpack_u4(u, ev);
    #pragma unroll
    for (int e = 0; e < 8; ++e) {
      float dv = ev[e] - zp[j * 8 + e];
      lsum = fmaf(dv, dv, lsum);
    }
  }
  for (int o = 32; o > 0; o >>= 1) lsum += __shfl_down(lsum, o, 64);
  if ((threadIdx.x & 63) == 0) atomicAdd(loss_acc, lsum);
}

// ----------------------------------------- final convT(64->3) + sigmoid
__global__ __launch_bounds__(256) void final_convt_sig(
    const bf16* __restrict__ hp, const float* __restrict__ wf,
    const float* __restrict__ bf_, float* __restrict__ out) {
  int tid = blockIdx.x * 256 + threadIdx.x;   // 16*256*256
  int ow = tid & 255; int t = tid >> 8;
  int oh = t & 255; int b = t >> 8;
  int p = oh & 1, y = oh >> 1, q = ow & 1, xx = ow >> 1;
  float a0 = bf_[0], a1 = bf_[1], a2 = bf_[2];
  const bf16* hb = hp + (long)b * 1081600;
  #pragma unroll
  for (int s = 0; s < 2; ++s) {
    #pragma unroll
    for (int t2 = 0; t2 < 2; ++t2) {
      int khkw = (2 * s + 1 - p) * 4 + (2 * t2 + 1 - q);
      const uint4* r4 = (const uint4*)(hb + (long)(y + p - s + 1) * 8320 +
                                       (long)(xx + q - t2 + 1) * 64);
      #pragma unroll
      for (int j = 0; j < 8; ++j) {
        float v[8];
        unpack_u4(r4[j], v);
        #pragma unroll
        for (int e = 0; e < 8; ++e) {
          const float* wc = wf + (j * 8 + e) * 48 + khkw;
          a0 = fmaf(v[e], wc[0], a0);
          a1 = fmaf(v[e], wc[16], a1);
          a2 = fmaf(v[e], wc[32], a2);
        }
      }
    }
  }
  long ob = (long)b * 196608 + (long)oh * 256 + ow;
  out[ob]          = 1.f / (1.f + expf(-a0));
  out[ob + 65536]  = 1.f / (1.f + expf(-a1));
  out[ob + 131072] = 1.f / (1.f + expf(-a2));
}

__global__ void finalize_loss_kernel(const float* __restrict__ lacc, float* __restrict__ out) {
  if (threadIdx.x == 0) {
    float lt = lacc[0] * (1.5f / 2097152.f);
    float lb = lacc[1] * (1.5f / 8388608.f);
    *out = lt + lb;
  }
}

// ------------------------------------------------------------------ launch
extern "C" void kernel_launch(void* const* d_in, const int* in_sizes, int n_in,
                              void* d_out, int out_size, void* d_ws, size_t ws_size,
                              hipStream_t stream) {
  float* out = (float*)d_out;
  char* base = (char*)d_ws;
  size_t off = 0;
  auto alloc = [&](size_t bytes) {
    void* pp = base + off;
    off = (off + bytes + 255) & ~(size_t)255;
    return pp;
  };

  int* flag = (int*)alloc(256);
  float* wB1f  = (float*)alloc(3072 * 4);   // conv1 weights [48][64]
  float* beB1f = (float*)alloc(64 * 4);
  float* beB2f = (float*)alloc(128 * 4);
  float* beTf  = (float*)alloc(128 * 4);
  float* bdTf  = (float*)alloc(128 * 4);
  float* bd1f  = (float*)alloc(64 * 4);
  float* wd2f  = (float*)alloc(3072 * 4);
  float* bd2f  = (float*)alloc(3 * 4);
  float* sqT   = (float*)alloc(512 * 4);
  float* sqB   = (float*)alloc(512 * 4);
  float* lacc  = (float*)alloc(2 * 4);
  bf16* Wt2  = (bf16*)alloc((size_t)131072 * 2);
  bf16* Wtt  = (bf16*)alloc((size_t)262144 * 2);
  bf16* Wdt  = (bf16*)alloc((size_t)262144 * 2);
  bf16* Wd1  = (bf16*)alloc((size_t)262144 * 2);
  bf16* embT = (bf16*)alloc((size_t)65536 * 2);
  bf16* embB = (bf16*)alloc((size_t)65536 * 2);
  bf16* act1p = (bf16*)alloc((size_t)17305600 * 2);  // [16][130][130][64]
  bf16* zbp   = (bf16*)alloc((size_t)8921088 * 2);   // [16][66][66][128]
  bf16* zqtp  = (bf16*)alloc((size_t)2367488 * 2);   // [16][34][34][128]
  bf16* eup   = (bf16*)alloc((size_t)8921088 * 2);   // [16][66][66][128]
  bf16* fqp   = (bf16*)alloc((size_t)8921088 * 2);   // [16][66][66][128]
  bf16* hp    = (bf16*)alloc((size_t)17305600 * 2);  // [16][130][130][64]
  bf16* ztp   = (bf16*)alloc((size_t)2097152 * 2);   // [16][32][32][128]

  const long actBytes = ((char*)(ztp + 2097152)) - ((char*)act1p);
  const long n4 = actBytes / 16;

  detect_dtype_kernel<<<1, 256, 0, stream>>>(d_in[0], flag);
  zero_kernel<<<4096, 256, 0, stream>>>((uint4*)act1p, n4);
  zero2_kernel<<<1, 64, 0, stream>>>(lacc);

  // converts / repacks
  rp_conv1_w<<<12, 256, 0, stream>>>(d_in[1], wB1f, flag);
  conv_f32<<<1, 256, 0, stream>>>(d_in[2], beB1f, 64, flag);
  conv_f32<<<1, 256, 0, stream>>>(d_in[4], beB2f, 128, flag);
  conv_f32<<<1, 256, 0, stream>>>(d_in[6], beTf, 128, flag);
  conv_f32<<<1, 256, 0, stream>>>(d_in[10], bdTf, 128, flag);
  conv_f32<<<1, 256, 0, stream>>>(d_in[12], bd1f, 64, flag);
  conv_f32<<<12, 256, 0, stream>>>(d_in[13], wd2f, 3072, flag);
  conv_f32<<<1, 256, 0, stream>>>(d_in[14], bd2f, 3, flag);
  conv_bf16<<<256, 256, 0, stream>>>(d_in[7], embT, 65536, flag);
  conv_bf16<<<256, 256, 0, stream>>>(d_in[8], embB, 65536, flag);
  embsq_kernel<<<2, 256, 0, stream>>>(embT, sqT);
  embsq_kernel<<<2, 256, 0, stream>>>(embB, sqB);
  rp_conv_w<128, 64><<<512, 256, 0, stream>>>(d_in[3], Wt2, flag);
  rp_conv_w<128, 128><<<1024, 256, 0, stream>>>(d_in[5], Wtt, flag);
  rp_convt_w<128, 128><<<1024, 256, 0, stream>>>(d_in[9], Wdt, flag);
  rp_convt_w<256, 64><<<1024, 256, 0, stream>>>(d_in[11], Wd1, flag);

  // encoder
  conv1_nhwc_v2<<<1024, 256, 0, stream>>>(d_in[0], flag, wB1f, beB1f, act1p);
  mfma_conv<128, 64, 64, 2, 16, 64><<<dim3(32, 2, 16), 256, 0, stream>>>(
      act1p, act1p, 1081600, 8320, Wt2, beB2f, zbp + 8576, 557568, 8448, 128, 0);
  mfma_conv<128, 128, 32, 2, 16, 128><<<dim3(8, 2, 16), 256, 0, stream>>>(
      zbp, zbp, 557568, 8448, Wtt, beTf, ztp, 131072, 4096, 128, 0);

  // VQ top
  vq_nhwc<<<64, 256, 0, stream>>>(ztp, 131072, 4096, embT, sqT,
                                  zqtp + 4480, 147968, 4352, lacc + 0, 1024, 32);

  // decoder_top upsample: 4 parity classes
  for (int cls = 0; cls < 4; ++cls) {
    int p = cls >> 1, q = cls & 1;
    mfma_conv<128, 128, 32, 1, 4, 128><<<dim3(8, 2, 16), 256, 0, stream>>>(
        zqtp, zqtp, 147968, 4352, Wdt + (long)cls * 65536, bdTf,
        eup + (long)(p + 1) * 8448 + (q + 1) * 128, 557568, 16896, 256, cls);
  }

  // VQ bottom
  vq_nhwc<<<256, 256, 0, stream>>>(zbp + 8576, 557568, 8448, embB, sqB,
                                   fqp + 8576, 557568, 8448, lacc + 1, 4096, 64);

  // decoder conv: concat(Fq, Eu) -> h (4 parity classes)
  for (int cls = 0; cls < 4; ++cls) {
    int p = cls >> 1, q = cls & 1;
    mfma_conv<64, 256, 64, 1, 4, 128><<<dim3(32, 1, 16), 256, 0, stream>>>(
        fqp, eup, 557568, 8448, Wd1 + (long)cls * 65536, bd1f,
        hp + (long)(p + 1) * 8320 + (q + 1) * 64, 1081600, 16640, 128, cls);
  }

  // final convT + sigmoid -> fp32 NCHW output
  final_convt_sig<<<4096, 256, 0, stream>>>(hp, wd2f, bd2f, out);
  finalize_loss_kernel<<<1, 64, 0, stream>>>(lacc, out + 3145728);
}

// Round 6
// 1395.516 us; speedup vs baseline: 2.3036x; 2.3036x over previous
//
#include <hip/hip_runtime.h>
#include <hip/hip_bf16.h>
#include <cstddef>

typedef __hip_bfloat16 bf16;
typedef __attribute__((ext_vector_type(8))) short short8;
typedef __attribute__((ext_vector_type(4))) float float4v;
typedef __attribute__((ext_vector_type(4))) unsigned short ushort4v;

static __device__ __forceinline__ float b2f(bf16 v) { return __bfloat162float(v); }
static __device__ __forceinline__ float bits2f(unsigned int u) { return __uint_as_float(u); }
static __device__ __forceinline__ unsigned short f2bfbits(float f) {
  bf16 h = __float2bfloat16(f);
  return *reinterpret_cast<unsigned short*>(&h);
}
static __device__ __forceinline__ float ld_any(const void* p, long i, int flag) {
  return flag ? b2f(((const bf16*)p)[i]) : ((const float*)p)[i];
}
static __device__ __forceinline__ void unpack_u4(uint4 u, float* f) {
  f[0] = bits2f(u.x << 16); f[1] = bits2f(u.x & 0xffff0000u);
  f[2] = bits2f(u.y << 16); f[3] = bits2f(u.y & 0xffff0000u);
  f[4] = bits2f(u.z << 16); f[5] = bits2f(u.z & 0xffff0000u);
  f[6] = bits2f(u.w << 16); f[7] = bits2f(u.w & 0xffff0000u);
}

// --------------------------------------------------------- dtype detection
__global__ void detect_dtype_kernel(const void* __restrict__ x, int* __restrict__ flag) {
  __shared__ int ok;
  if (threadIdx.x == 0) ok = 1;
  __syncthreads();
  float v = b2f(((const bf16*)x)[threadIdx.x]);
  if (!(v >= 0.f && v <= 1.0009765625f)) ok = 0;
  __syncthreads();
  if (threadIdx.x == 0) *flag = ok;
}

// ---------------------------------------------------------------- utilities
__global__ void zero_kernel(uint4* __restrict__ p, long n4) {
  long i = (long)blockIdx.x * blockDim.x + threadIdx.x;
  long stride = (long)gridDim.x * blockDim.x;
  uint4 z = {0u, 0u, 0u, 0u};
  for (; i < n4; i += stride) p[i] = z;
}
__global__ void zero2_kernel(float* p) {
  if (threadIdx.x < 2) p[threadIdx.x] = 0.f;
}
__global__ void conv_f32(const void* __restrict__ src, float* __restrict__ dst,
                         int n, const int* __restrict__ flag) {
  int i = blockIdx.x * blockDim.x + threadIdx.x;
  if (i < n) dst[i] = ld_any(src, i, *flag);
}
__global__ void conv_bf16(const void* __restrict__ src, bf16* __restrict__ dst,
                          int n, const int* __restrict__ flag) {
  int i = blockIdx.x * blockDim.x + threadIdx.x;
  if (i >= n) return;
  dst[i] = (*flag) ? ((const bf16*)src)[i] : __float2bfloat16(((const float*)src)[i]);
}
__global__ void embsq_kernel(const bf16* __restrict__ emb, float* __restrict__ out) {
  int k = blockIdx.x * blockDim.x + threadIdx.x;
  if (k >= 512) return;
  float s = 0.f;
  for (int c = 0; c < 128; ++c) { float e = b2f(emb[k * 128 + c]); s = fmaf(e, e, s); }
  out[k] = s;
}

// conv1 weights [64][3][4][4] -> [co][k] bf16, K padded 48->64 with zeros
__global__ void rp_c1w(const void* __restrict__ src, bf16* __restrict__ dst,
                       const int* __restrict__ flag) {
  int i = blockIdx.x * blockDim.x + threadIdx.x;   // 64*64
  if (i >= 4096) return;
  int co = i >> 6, k = i & 63;
  float v = (k < 48) ? ld_any(src, co * 48 + k, *flag) : 0.f;
  dst[i] = __float2bfloat16(v);
}

// weights OIHW [CO][CI][4][4] -> [tap=kh*4+kw][co][ci] bf16
template <int CO, int CI>
__global__ void rp_conv_w(const void* __restrict__ src, bf16* __restrict__ dst,
                          const int* __restrict__ flag) {
  const int N = CO * CI * 16;
  int i = blockIdx.x * blockDim.x + threadIdx.x;
  if (i >= N) return;
  int co = i / (CI * 16);
  int rem = i % (CI * 16);
  int ci = rem >> 4;
  int k = rem & 15;
  dst[((long)k * CO + co) * CI + ci] = __float2bfloat16(ld_any(src, i, *flag));
}

// convT weights [CI][CO][4][4] -> [class pq][tap st][co][ci] bf16
template <int CI, int CO>
__global__ void rp_convt_w(const void* __restrict__ src, bf16* __restrict__ dst,
                           const int* __restrict__ flag) {
  const int N = CI * CO * 16;
  int i = blockIdx.x * blockDim.x + threadIdx.x;
  if (i >= N) return;
  int ci = i / (CO * 16);
  int rem = i % (CO * 16);
  int co = rem >> 4;
  int k = rem & 15;
  int kh = k >> 2, kw = k & 3;
  int p = (kh + 1) & 1, s = (kh - 1 + p) >> 1;
  int q = (kw + 1) & 1, t = (kw - 1 + q) >> 1;
  long d = (((long)(p * 2 + q) * 4 + (s * 2 + t)) * CO + co) * CI + ci;
  dst[d] = __float2bfloat16(ld_any(src, i, *flag));
}

// -------------------- conv1 as GEMM: im2col (K padded to 64) + MFMA GEMM
__global__ __launch_bounds__(256) void im2col1(const void* __restrict__ x,
                                               const int* __restrict__ flag,
                                               bf16* __restrict__ col) {
  int tid = blockIdx.x * 256 + threadIdx.x;   // 16*128*128
  int ow = tid & 127; int t = tid >> 7;
  int oh = t & 127; int b = t >> 7;
  int fl = *flag;
  int ih0 = oh * 2 - 1, iw0 = ow * 2 - 1;
  unsigned short vals[64];
  #pragma unroll
  for (int j = 48; j < 64; ++j) vals[j] = 0;
  #pragma unroll
  for (int ci = 0; ci < 3; ++ci) {
    long pbase = ((long)(b * 3 + ci)) << 16;
    #pragma unroll
    for (int kh = 0; kh < 4; ++kh) {
      int ih = ih0 + kh;
      bool okh = (unsigned)ih < 256u;
      long rbase = pbase + ((long)ih << 8);
      #pragma unroll
      for (int kw = 0; kw < 4; ++kw) {
        int iw = iw0 + kw;
        float v = (okh && (unsigned)iw < 256u) ? ld_any(x, rbase + iw, fl) : 0.f;
        vals[ci * 16 + kh * 4 + kw] = f2bfbits(v);
      }
    }
  }
  uint4* dst = (uint4*)(col + (long)tid * 64);
  const uint4* s = (const uint4*)vals;
  #pragma unroll
  for (int j = 0; j < 8; ++j) dst[j] = s[j];
}

// M=64 (co), K=64, N=262144 (positions); bias+relu; store padded NHWC
__global__ __launch_bounds__(256) void gemm1(const bf16* __restrict__ col,
                                             const bf16* __restrict__ w,
                                             const float* __restrict__ bias,
                                             bf16* __restrict__ act1p) {
  const int lane = threadIdx.x & 63, wv = threadIdx.x >> 6;
  const int wm = wv & 1, wn = wv >> 1;
  const int ln = lane & 15, quad = lane >> 4;
  const int n0 = blockIdx.x * 128 + wn * 64;
  float4v acc[2][4];
  #pragma unroll
  for (int i = 0; i < 2; ++i)
    #pragma unroll
    for (int j = 0; j < 4; ++j) acc[i][j] = {0.f, 0.f, 0.f, 0.f};
  #pragma unroll
  for (int kc = 0; kc < 2; ++kc) {
    const bf16* wk = w + (wm * 32 + ln) * 64 + kc * 32 + quad * 8;
    short8 a0 = *(const short8*)(wk);
    short8 a1 = *(const short8*)(wk + 16 * 64);
    #pragma unroll
    for (int bf = 0; bf < 4; ++bf) {
      short8 bv = *(const short8*)(col + (long)(n0 + bf * 16 + ln) * 64 + kc * 32 + quad * 8);
      acc[0][bf] = __builtin_amdgcn_mfma_f32_16x16x32_bf16(a0, bv, acc[0][bf], 0, 0, 0);
      acc[1][bf] = __builtin_amdgcn_mfma_f32_16x16x32_bf16(a1, bv, acc[1][bf], 0, 0, 0);
    }
  }
  #pragma unroll
  for (int mf = 0; mf < 2; ++mf) {
    int coB = wm * 32 + mf * 16 + quad * 4;
    float4v bv4 = *(const float4v*)(bias + coB);
    #pragma unroll
    for (int bf = 0; bf < 4; ++bf) {
      int n = n0 + bf * 16 + ln;
      int ow = n & 127; int t2 = n >> 7;
      int oh = t2 & 127; int b = t2 >> 7;
      long oaddr = ((long)(b * 130 + oh + 1) * 130 + ow + 1) * 64 + coB;
      float4v v = acc[mf][bf];
      ushort4v o;
      #pragma unroll
      for (int e = 0; e < 4; ++e) o[e] = f2bfbits(fmaxf(v[e] + bv4[e], 0.f));
      *(ushort4v*)(act1p + oaddr) = o;
    }
  }
}

// ------------------------------------------- MFMA implicit-GEMM tap conv
template <int COUT, int CINT, int TC, int S, int NT, int INC>
__global__ __launch_bounds__(256) void mfma_conv(
    const bf16* __restrict__ in1, const bf16* __restrict__ in2,
    long inImgS, int inRowS,
    const bf16* __restrict__ w, const float* __restrict__ bias,
    bf16* __restrict__ outp, long outImgS, int oRS, int oCS, int pq) {
  constexpr int TR = 128 / TC;
  constexpr int KC = CINT / 32;
  constexpr int KSPLIT = (CINT > INC) ? (INC / 32) : KC;
  const int lane = threadIdx.x & 63;
  const int wv = threadIdx.x >> 6;
  const int wm = wv & 1, wn = wv >> 1;
  const int ln = lane & 15, quad = lane >> 4;
  const int mTile = blockIdx.y * 64;
  const int oh0 = blockIdx.x * TR;
  const int b = blockIdx.z;
  const int p = pq >> 1, q = pq & 1;

  long posOff[4];
  int rr[4], cc[4];
  #pragma unroll
  for (int bf = 0; bf < 4; ++bf) {
    int n = wn * 64 + bf * 16 + ln;
    int r = n / TC, c = n % TC;
    rr[bf] = r; cc[bf] = c;
    posOff[bf] = (long)(S * (oh0 + r)) * inRowS + (long)(S * c) * INC;
  }
  const bf16* inb1 = in1 + (long)b * inImgS;
  const bf16* inb2 = in2 + (long)b * inImgS;

  float4v acc[2][4];
  #pragma unroll
  for (int i = 0; i < 2; ++i)
    #pragma unroll
    for (int j = 0; j < 4; ++j) acc[i][j] = {0.f, 0.f, 0.f, 0.f};

  for (int t = 0; t < NT; ++t) {
    int dy, dx;
    if (S == 2) { dy = t >> 2; dx = t & 3; }
    else        { dy = p - (t >> 1) + 1; dx = q - (t & 1) + 1; }
    const long tapOff = (long)dy * inRowS + (long)dx * INC;
    const bf16* wt = w + (long)t * COUT * CINT;
    const bf16* wk0 = wt + (long)(mTile + wm * 32 + ln) * CINT + quad * 8;
    #pragma unroll
    for (int kc = 0; kc < KC; ++kc) {
      short8 a0 = *(const short8*)(wk0 + kc * 32);
      short8 a1 = *(const short8*)(wk0 + kc * 32 + 16 * CINT);
      const bf16* bp = (kc < KSPLIT) ? inb1 : inb2;
      int kOff = (kc < KSPLIT ? kc : kc - KSPLIT) * 32 + quad * 8;
      #pragma unroll
      for (int bf = 0; bf < 4; ++bf) {
        short8 bv = *(const short8*)(bp + posOff[bf] + tapOff + kOff);
        acc[0][bf] = __builtin_amdgcn_mfma_f32_16x16x32_bf16(a0, bv, acc[0][bf], 0, 0, 0);
        acc[1][bf] = __builtin_amdgcn_mfma_f32_16x16x32_bf16(a1, bv, acc[1][bf], 0, 0, 0);
      }
    }
  }

  bf16* outb = outp + (long)b * outImgS;
  #pragma unroll
  for (int mf = 0; mf < 2; ++mf) {
    int coB = mTile + wm * 32 + mf * 16 + quad * 4;
    float4v bv4 = *(const float4v*)(bias + coB);
    #pragma unroll
    for (int bf = 0; bf < 4; ++bf) {
      float4v v = acc[mf][bf];
      ushort4v o;
      #pragma unroll
      for (int e = 0; e < 4; ++e)
        o[e] = f2bfbits(fmaxf(v[e] + bv4[e], 0.f));
      long oaddr = (long)(oh0 + rr[bf]) * oRS + (long)cc[bf] * oCS + coB;
      *(ushort4v*)(outb + oaddr) = o;
    }
  }
}

// ------------------------------------------------------------- VQ quantize
__global__ __launch_bounds__(256) void vq_nhwc(
    const bf16* __restrict__ z, long zImgS, int zRowS,
    const bf16* __restrict__ emb, const float* __restrict__ embsq,
    bf16* __restrict__ zq, long qImgS, int qRowS,
    float* __restrict__ loss_acc, int HW, int Wv) {
  __shared__ float se[64 * 128];
  __shared__ float ssq[64];
  const int n = blockIdx.x * 256 + threadIdx.x;
  const int b = n / HW, rem = n % HW;
  const int y = rem / Wv, xx = rem % Wv;
  const bf16* zrow = z + (long)b * zImgS + (long)y * zRowS + (long)xx * 128;
  float zp[128];
  {
    const uint4* zr4 = (const uint4*)zrow;
    #pragma unroll
    for (int j = 0; j < 16; ++j) unpack_u4(zr4[j], zp + j * 8);
  }
  float best = 3.4e38f; int bestk = 0;
  for (int k0 = 0; k0 < 512; k0 += 64) {
    __syncthreads();
    #pragma unroll
    for (int tt = 0; tt < 32; ++tt) {
      int idx = tt * 256 + threadIdx.x;
      se[idx] = b2f(emb[(long)k0 * 128 + idx]);
    }
    if (threadIdx.x < 64) ssq[threadIdx.x] = embsq[k0 + threadIdx.x];
    __syncthreads();
    for (int kk = 0; kk < 64; kk += 4) {
      float d0 = 0.f, d1 = 0.f, d2 = 0.f, d3 = 0.f;
      const float* e0 = se + kk * 128;
      #pragma unroll
      for (int c = 0; c < 128; ++c) {
        float zc = zp[c];
        d0 = fmaf(zc, e0[c], d0);
        d1 = fmaf(zc, e0[128 + c], d1);
        d2 = fmaf(zc, e0[256 + c], d2);
        d3 = fmaf(zc, e0[384 + c], d3);
      }
      float s0 = fmaf(-2.f, d0, ssq[kk + 0]);
      float s1 = fmaf(-2.f, d1, ssq[kk + 1]);
      float s2 = fmaf(-2.f, d2, ssq[kk + 2]);
      float s3 = fmaf(-2.f, d3, ssq[kk + 3]);
      if (s0 < best) { best = s0; bestk = k0 + kk + 0; }
      if (s1 < best) { best = s1; bestk = k0 + kk + 1; }
      if (s2 < best) { best = s2; bestk = k0 + kk + 2; }
      if (s3 < best) { best = s3; bestk = k0 + kk + 3; }
    }
  }
  const uint4* er = (const uint4*)(emb + (long)bestk * 128);
  uint4* qrow = (uint4*)(zq + (long)b * qImgS + (long)y * qRowS + (long)xx * 128);
  float lsum = 0.f;
  #pragma unroll
  for (int j = 0; j < 16; ++j) {
    uint4 u = er[j];
    qrow[j] = u;
    float ev[8];
    unpack_u4(u, ev);
    #pragma unroll
    for (int e = 0; e < 8; ++e) {
      float dv = ev[e] - zp[j * 8 + e];
      lsum = fmaf(dv, dv, lsum);
    }
  }
  for (int o = 32; o > 0; o >>= 1) lsum += __shfl_down(lsum, o, 64);
  if ((threadIdx.x & 63) == 0) atomicAdd(loss_acc, lsum);
}

// ----------------------------------------- final convT(64->3) + sigmoid
__global__ __launch_bounds__(256) void final_convt_sig(
    const bf16* __restrict__ hp, const float* __restrict__ wf,
    const float* __restrict__ bf_, float* __restrict__ out) {
  int tid = blockIdx.x * 256 + threadIdx.x;   // 16*256*256
  int ow = tid & 255; int t = tid >> 8;
  int oh = t & 255; int b = t >> 8;
  int p = oh & 1, y = oh >> 1, q = ow & 1, xx = ow >> 1;
  float a0 = bf_[0], a1 = bf_[1], a2 = bf_[2];
  const bf16* hb = hp + (long)b * 1081600;
  #pragma unroll
  for (int s = 0; s < 2; ++s) {
    #pragma unroll
    for (int t2 = 0; t2 < 2; ++t2) {
      int khkw = (2 * s + 1 - p) * 4 + (2 * t2 + 1 - q);
      const uint4* r4 = (const uint4*)(hb + (long)(y + p - s + 1) * 8320 +
                                       (long)(xx + q - t2 + 1) * 64);
      #pragma unroll
      for (int j = 0; j < 8; ++j) {
        float v[8];
        unpack_u4(r4[j], v);
        #pragma unroll
        for (int e = 0; e < 8; ++e) {
          const float* wc = wf + (j * 8 + e) * 48 + khkw;
          a0 = fmaf(v[e], wc[0], a0);
          a1 = fmaf(v[e], wc[16], a1);
          a2 = fmaf(v[e], wc[32], a2);
        }
      }
    }
  }
  long ob = (long)b * 196608 + (long)oh * 256 + ow;
  out[ob]          = 1.f / (1.f + expf(-a0));
  out[ob + 65536]  = 1.f / (1.f + expf(-a1));
  out[ob + 131072] = 1.f / (1.f + expf(-a2));
}

__global__ void finalize_loss_kernel(const float* __restrict__ lacc, float* __restrict__ out) {
  if (threadIdx.x == 0) {
    float lt = lacc[0] * (1.5f / 2097152.f);
    float lb = lacc[1] * (1.5f / 8388608.f);
    *out = lt + lb;
  }
}

// ------------------------------------------------------------------ launch
extern "C" void kernel_launch(void* const* d_in, const int* in_sizes, int n_in,
                              void* d_out, int out_size, void* d_ws, size_t ws_size,
                              hipStream_t stream) {
  float* out = (float*)d_out;
  char* base = (char*)d_ws;
  size_t off = 0;
  auto alloc = [&](size_t bytes) {
    void* pp = base + off;
    off = (off + bytes + 255) & ~(size_t)255;
    return pp;
  };

  int* flag = (int*)alloc(256);
  float* beB1f = (float*)alloc(64 * 4);
  float* beB2f = (float*)alloc(128 * 4);
  float* beTf  = (float*)alloc(128 * 4);
  float* bdTf  = (float*)alloc(128 * 4);
  float* bd1f  = (float*)alloc(64 * 4);
  float* wd2f  = (float*)alloc(3072 * 4);
  float* bd2f  = (float*)alloc(3 * 4);
  float* sqT   = (float*)alloc(512 * 4);
  float* sqB   = (float*)alloc(512 * 4);
  float* lacc  = (float*)alloc(2 * 4);
  bf16* Wc1  = (bf16*)alloc((size_t)4096 * 2);    // conv1 [64co][64k]
  bf16* Wt2  = (bf16*)alloc((size_t)131072 * 2);
  bf16* Wtt  = (bf16*)alloc((size_t)262144 * 2);
  bf16* Wdt  = (bf16*)alloc((size_t)262144 * 2);
  bf16* Wd1  = (bf16*)alloc((size_t)262144 * 2);
  bf16* embT = (bf16*)alloc((size_t)65536 * 2);
  bf16* embB = (bf16*)alloc((size_t)65536 * 2);
  bf16* colb = (bf16*)alloc((size_t)16777216 * 2);   // im2col [262144][64]
  bf16* act1p = (bf16*)alloc((size_t)17305600 * 2);  // [16][130][130][64]
  bf16* zbp   = (bf16*)alloc((size_t)8921088 * 2);   // [16][66][66][128]
  bf16* zqtp  = (bf16*)alloc((size_t)2367488 * 2);   // [16][34][34][128]
  bf16* eup   = (bf16*)alloc((size_t)8921088 * 2);   // [16][66][66][128]
  bf16* fqp   = (bf16*)alloc((size_t)8921088 * 2);   // [16][66][66][128]
  bf16* hp    = (bf16*)alloc((size_t)17305600 * 2);  // [16][130][130][64]
  bf16* ztp   = (bf16*)alloc((size_t)2097152 * 2);   // [16][32][32][128]

  const long actBytes = ((char*)(ztp + 2097152)) - ((char*)act1p);
  const long n4 = actBytes / 16;

  detect_dtype_kernel<<<1, 256, 0, stream>>>(d_in[0], flag);
  zero_kernel<<<4096, 256, 0, stream>>>((uint4*)act1p, n4);
  zero2_kernel<<<1, 64, 0, stream>>>(lacc);

  // converts / repacks
  rp_c1w<<<16, 256, 0, stream>>>(d_in[1], Wc1, flag);
  conv_f32<<<1, 256, 0, stream>>>(d_in[2], beB1f, 64, flag);
  conv_f32<<<1, 256, 0, stream>>>(d_in[4], beB2f, 128, flag);
  conv_f32<<<1, 256, 0, stream>>>(d_in[6], beTf, 128, flag);
  conv_f32<<<1, 256, 0, stream>>>(d_in[10], bdTf, 128, flag);
  conv_f32<<<1, 256, 0, stream>>>(d_in[12], bd1f, 64, flag);
  conv_f32<<<12, 256, 0, stream>>>(d_in[13], wd2f, 3072, flag);
  conv_f32<<<1, 256, 0, stream>>>(d_in[14], bd2f, 3, flag);
  conv_bf16<<<256, 256, 0, stream>>>(d_in[7], embT, 65536, flag);
  conv_bf16<<<256, 256, 0, stream>>>(d_in[8], embB, 65536, flag);
  embsq_kernel<<<2, 256, 0, stream>>>(embT, sqT);
  embsq_kernel<<<2, 256, 0, stream>>>(embB, sqB);
  rp_conv_w<128, 64><<<512, 256, 0, stream>>>(d_in[3], Wt2, flag);
  rp_conv_w<128, 128><<<1024, 256, 0, stream>>>(d_in[5], Wtt, flag);
  rp_convt_w<128, 128><<<1024, 256, 0, stream>>>(d_in[9], Wdt, flag);
  rp_convt_w<256, 64><<<1024, 256, 0, stream>>>(d_in[11], Wd1, flag);

  // encoder: conv1 = im2col + MFMA GEMM
  im2col1<<<1024, 256, 0, stream>>>(d_in[0], flag, colb);
  gemm1<<<2048, 256, 0, stream>>>(colb, Wc1, beB1f, act1p);
  mfma_conv<128, 64, 64, 2, 16, 64><<<dim3(32, 2, 16), 256, 0, stream>>>(
      act1p, act1p, 1081600, 8320, Wt2, beB2f, zbp + 8576, 557568, 8448, 128, 0);
  mfma_conv<128, 128, 32, 2, 16, 128><<<dim3(8, 2, 16), 256, 0, stream>>>(
      zbp, zbp, 557568, 8448, Wtt, beTf, ztp, 131072, 4096, 128, 0);

  // VQ top
  vq_nhwc<<<64, 256, 0, stream>>>(ztp, 131072, 4096, embT, sqT,
                                  zqtp + 4480, 147968, 4352, lacc + 0, 1024, 32);

  // decoder_top upsample: 4 parity classes
  for (int cls = 0; cls < 4; ++cls) {
    int p = cls >> 1, q = cls & 1;
    mfma_conv<128, 128, 32, 1, 4, 128><<<dim3(8, 2, 16), 256, 0, stream>>>(
        zqtp, zqtp, 147968, 4352, Wdt + (long)cls * 65536, bdTf,
        eup + (long)(p + 1) * 8448 + (q + 1) * 128, 557568, 16896, 256, cls);
  }

  // VQ bottom
  vq_nhwc<<<256, 256, 0, stream>>>(zbp + 8576, 557568, 8448, embB, sqB,
                                   fqp + 8576, 557568, 8448, lacc + 1, 4096, 64);

  // decoder conv: concat(Fq, Eu) -> h (4 parity classes)
  for (int cls = 0; cls < 4; ++cls) {
    int p = cls >> 1, q = cls & 1;
    mfma_conv<64, 256, 64, 1, 4, 128><<<dim3(32, 1, 16), 256, 0, stream>>>(
        fqp, eup, 557568, 8448, Wd1 + (long)cls * 65536, bd1f,
        hp + (long)(p + 1) * 8320 + (q + 1) * 64, 1081600, 16640, 128, cls);
  }

  // final convT + sigmoid -> fp32 NCHW output
  final_convt_sig<<<4096, 256, 0, stream>>>(hp, wd2f, bd2f, out);
  finalize_loss_kernel<<<1, 64, 0, stream>>>(lacc, out + 3145728);
}

// Round 7
// 834.477 us; speedup vs baseline: 3.8523x; 1.6723x over previous
//
#include <hip/hip_runtime.h>
#include <hip/hip_bf16.h>
#include <cstddef>

typedef __hip_bfloat16 bf16;
typedef __attribute__((ext_vector_type(8))) short short8;
typedef __attribute__((ext_vector_type(4))) float float4v;
typedef __attribute__((ext_vector_type(4))) unsigned short ushort4v;

static __device__ __forceinline__ float b2f(bf16 v) { return __bfloat162float(v); }
static __device__ __forceinline__ float bits2f(unsigned int u) { return __uint_as_float(u); }
static __device__ __forceinline__ unsigned short f2bfbits(float f) {
  bf16 h = __float2bfloat16(f);
  return *reinterpret_cast<unsigned short*>(&h);
}
static __device__ __forceinline__ float ld_any(const void* p, long i, int flag) {
  return flag ? b2f(((const bf16*)p)[i]) : ((const float*)p)[i];
}
static __device__ __forceinline__ void unpack_u4(uint4 u, float* f) {
  f[0] = bits2f(u.x << 16); f[1] = bits2f(u.x & 0xffff0000u);
  f[2] = bits2f(u.y << 16); f[3] = bits2f(u.y & 0xffff0000u);
  f[4] = bits2f(u.z << 16); f[5] = bits2f(u.z & 0xffff0000u);
  f[6] = bits2f(u.w << 16); f[7] = bits2f(u.w & 0xffff0000u);
}

// --------------------------------------------------------- dtype detection
__global__ void detect_dtype_kernel(const void* __restrict__ x, int* __restrict__ flag) {
  __shared__ int ok;
  if (threadIdx.x == 0) ok = 1;
  __syncthreads();
  float v = b2f(((const bf16*)x)[threadIdx.x]);
  if (!(v >= 0.f && v <= 1.0009765625f)) ok = 0;
  __syncthreads();
  if (threadIdx.x == 0) *flag = ok;
}

// ---------------------------------------------------------------- utilities
__global__ void zero_kernel(uint4* __restrict__ p, long n4) {
  long i = (long)blockIdx.x * blockDim.x + threadIdx.x;
  long stride = (long)gridDim.x * blockDim.x;
  uint4 z = {0u, 0u, 0u, 0u};
  for (; i < n4; i += stride) p[i] = z;
}
__global__ void zero2_kernel(float* p) {
  if (threadIdx.x < 2) p[threadIdx.x] = 0.f;
}
__global__ void conv_f32(const void* __restrict__ src, float* __restrict__ dst,
                         int n, const int* __restrict__ flag) {
  int i = blockIdx.x * blockDim.x + threadIdx.x;
  if (i < n) dst[i] = ld_any(src, i, *flag);
}
__global__ void conv_bf16(const void* __restrict__ src, bf16* __restrict__ dst,
                          int n, const int* __restrict__ flag) {
  int i = blockIdx.x * blockDim.x + threadIdx.x;
  if (i >= n) return;
  dst[i] = (*flag) ? ((const bf16*)src)[i] : __float2bfloat16(((const float*)src)[i]);
}
__global__ void embsq_kernel(const bf16* __restrict__ emb, float* __restrict__ out) {
  int k = blockIdx.x * blockDim.x + threadIdx.x;
  if (k >= 512) return;
  float s = 0.f;
  for (int c = 0; c < 128; ++c) { float e = b2f(emb[k * 128 + c]); s = fmaf(e, e, s); }
  out[k] = s;
}

// conv1 weights [64][3][4][4] -> [co][k] bf16, K padded 48->64 with zeros
__global__ void rp_c1w(const void* __restrict__ src, bf16* __restrict__ dst,
                       const int* __restrict__ flag) {
  int i = blockIdx.x * blockDim.x + threadIdx.x;   // 64*64
  if (i >= 4096) return;
  int co = i >> 6, k = i & 63;
  float v = (k < 48) ? ld_any(src, co * 48 + k, *flag) : 0.f;
  dst[i] = __float2bfloat16(v);
}

// weights OIHW [CO][CI][4][4] -> [tap=kh*4+kw][co][ci] bf16
template <int CO, int CI>
__global__ void rp_conv_w(const void* __restrict__ src, bf16* __restrict__ dst,
                          const int* __restrict__ flag) {
  const int N = CO * CI * 16;
  int i = blockIdx.x * blockDim.x + threadIdx.x;
  if (i >= N) return;
  int co = i / (CI * 16);
  int rem = i % (CI * 16);
  int ci = rem >> 4;
  int k = rem & 15;
  dst[((long)k * CO + co) * CI + ci] = __float2bfloat16(ld_any(src, i, *flag));
}

// convT weights [CI][CO][4][4] -> [class pq][tap st][co][ci] bf16
template <int CI, int CO>
__global__ void rp_convt_w(const void* __restrict__ src, bf16* __restrict__ dst,
                           const int* __restrict__ flag) {
  const int N = CI * CO * 16;
  int i = blockIdx.x * blockDim.x + threadIdx.x;
  if (i >= N) return;
  int ci = i / (CO * 16);
  int rem = i % (CO * 16);
  int co = rem >> 4;
  int k = rem & 15;
  int kh = k >> 2, kw = k & 3;
  int p = (kh + 1) & 1, s = (kh - 1 + p) >> 1;
  int q = (kw + 1) & 1, t = (kw - 1 + q) >> 1;
  long d = (((long)(p * 2 + q) * 4 + (s * 2 + t)) * CO + co) * CI + ci;
  dst[d] = __float2bfloat16(ld_any(src, i, *flag));
}

// -------------------- conv1 as GEMM: im2col (K padded to 64) + MFMA GEMM
__global__ __launch_bounds__(256) void im2col1(const void* __restrict__ x,
                                               const int* __restrict__ flag,
                                               bf16* __restrict__ col) {
  int tid = blockIdx.x * 256 + threadIdx.x;   // 16*128*128
  int ow = tid & 127; int t = tid >> 7;
  int oh = t & 127; int b = t >> 7;
  int fl = *flag;
  int ih0 = oh * 2 - 1, iw0 = ow * 2 - 1;
  unsigned short vals[64];
  #pragma unroll
  for (int j = 48; j < 64; ++j) vals[j] = 0;
  #pragma unroll
  for (int ci = 0; ci < 3; ++ci) {
    long pbase = ((long)(b * 3 + ci)) << 16;
    #pragma unroll
    for (int kh = 0; kh < 4; ++kh) {
      int ih = ih0 + kh;
      bool okh = (unsigned)ih < 256u;
      long rbase = pbase + ((long)ih << 8);
      #pragma unroll
      for (int kw = 0; kw < 4; ++kw) {
        int iw = iw0 + kw;
        float v = (okh && (unsigned)iw < 256u) ? ld_any(x, rbase + iw, fl) : 0.f;
        vals[ci * 16 + kh * 4 + kw] = f2bfbits(v);
      }
    }
  }
  uint4* dst = (uint4*)(col + (long)tid * 64);
  const uint4* s = (const uint4*)vals;
  #pragma unroll
  for (int j = 0; j < 8; ++j) dst[j] = s[j];
}

// M=64 (co), K=64, N=262144 (positions); bias+relu; store padded NHWC
__global__ __launch_bounds__(256) void gemm1(const bf16* __restrict__ col,
                                             const bf16* __restrict__ w,
                                             const float* __restrict__ bias,
                                             bf16* __restrict__ act1p) {
  const int lane = threadIdx.x & 63, wv = threadIdx.x >> 6;
  const int wm = wv & 1, wn = wv >> 1;
  const int ln = lane & 15, quad = lane >> 4;
  const int n0 = blockIdx.x * 128 + wn * 64;
  float4v acc[2][4];
  #pragma unroll
  for (int i = 0; i < 2; ++i)
    #pragma unroll
    for (int j = 0; j < 4; ++j) acc[i][j] = {0.f, 0.f, 0.f, 0.f};
  #pragma unroll
  for (int kc = 0; kc < 2; ++kc) {
    const bf16* wk = w + (wm * 32 + ln) * 64 + kc * 32 + quad * 8;
    short8 a0 = *(const short8*)(wk);
    short8 a1 = *(const short8*)(wk + 16 * 64);
    #pragma unroll
    for (int bf = 0; bf < 4; ++bf) {
      short8 bv = *(const short8*)(col + (long)(n0 + bf * 16 + ln) * 64 + kc * 32 + quad * 8);
      acc[0][bf] = __builtin_amdgcn_mfma_f32_16x16x32_bf16(a0, bv, acc[0][bf], 0, 0, 0);
      acc[1][bf] = __builtin_amdgcn_mfma_f32_16x16x32_bf16(a1, bv, acc[1][bf], 0, 0, 0);
    }
  }
  #pragma unroll
  for (int mf = 0; mf < 2; ++mf) {
    int coB = wm * 32 + mf * 16 + quad * 4;
    float4v bv4 = *(const float4v*)(bias + coB);
    #pragma unroll
    for (int bf = 0; bf < 4; ++bf) {
      int n = n0 + bf * 16 + ln;
      int ow = n & 127; int t2 = n >> 7;
      int oh = t2 & 127; int b = t2 >> 7;
      long oaddr = ((long)(b * 130 + oh + 1) * 130 + ow + 1) * 64 + coB;
      float4v v = acc[mf][bf];
      ushort4v o;
      #pragma unroll
      for (int e = 0; e < 4; ++e) o[e] = f2bfbits(fmaxf(v[e] + bv4[e], 0.f));
      *(ushort4v*)(act1p + oaddr) = o;
    }
  }
}

// ------------------------------------------- MFMA implicit-GEMM tap conv
template <int COUT, int CINT, int TC, int S, int NT, int INC>
__global__ __launch_bounds__(256) void mfma_conv(
    const bf16* __restrict__ in1, const bf16* __restrict__ in2,
    long inImgS, int inRowS,
    const bf16* __restrict__ w, const float* __restrict__ bias,
    bf16* __restrict__ outp, long outImgS, int oRS, int oCS, int pq) {
  constexpr int TR = 128 / TC;
  constexpr int KC = CINT / 32;
  constexpr int KSPLIT = (CINT > INC) ? (INC / 32) : KC;
  const int lane = threadIdx.x & 63;
  const int wv = threadIdx.x >> 6;
  const int wm = wv & 1, wn = wv >> 1;
  const int ln = lane & 15, quad = lane >> 4;
  const int mTile = blockIdx.y * 64;
  const int oh0 = blockIdx.x * TR;
  const int b = blockIdx.z;
  const int p = pq >> 1, q = pq & 1;

  long posOff[4];
  int rr[4], cc[4];
  #pragma unroll
  for (int bf = 0; bf < 4; ++bf) {
    int n = wn * 64 + bf * 16 + ln;
    int r = n / TC, c = n % TC;
    rr[bf] = r; cc[bf] = c;
    posOff[bf] = (long)(S * (oh0 + r)) * inRowS + (long)(S * c) * INC;
  }
  const bf16* inb1 = in1 + (long)b * inImgS;
  const bf16* inb2 = in2 + (long)b * inImgS;

  float4v acc[2][4];
  #pragma unroll
  for (int i = 0; i < 2; ++i)
    #pragma unroll
    for (int j = 0; j < 4; ++j) acc[i][j] = {0.f, 0.f, 0.f, 0.f};

  for (int t = 0; t < NT; ++t) {
    int dy, dx;
    if (S == 2) { dy = t >> 2; dx = t & 3; }
    else        { dy = p - (t >> 1) + 1; dx = q - (t & 1) + 1; }
    const long tapOff = (long)dy * inRowS + (long)dx * INC;
    const bf16* wt = w + (long)t * COUT * CINT;
    const bf16* wk0 = wt + (long)(mTile + wm * 32 + ln) * CINT + quad * 8;
    #pragma unroll
    for (int kc = 0; kc < KC; ++kc) {
      short8 a0 = *(const short8*)(wk0 + kc * 32);
      short8 a1 = *(const short8*)(wk0 + kc * 32 + 16 * CINT);
      const bf16* bp = (kc < KSPLIT) ? inb1 : inb2;
      int kOff = (kc < KSPLIT ? kc : kc - KSPLIT) * 32 + quad * 8;
      #pragma unroll
      for (int bf = 0; bf < 4; ++bf) {
        short8 bv = *(const short8*)(bp + posOff[bf] + tapOff + kOff);
        acc[0][bf] = __builtin_amdgcn_mfma_f32_16x16x32_bf16(a0, bv, acc[0][bf], 0, 0, 0);
        acc[1][bf] = __builtin_amdgcn_mfma_f32_16x16x32_bf16(a1, bv, acc[1][bf], 0, 0, 0);
      }
    }
  }

  bf16* outb = outp + (long)b * outImgS;
  #pragma unroll
  for (int mf = 0; mf < 2; ++mf) {
    int coB = mTile + wm * 32 + mf * 16 + quad * 4;
    float4v bv4 = *(const float4v*)(bias + coB);
    #pragma unroll
    for (int bf = 0; bf < 4; ++bf) {
      float4v v = acc[mf][bf];
      ushort4v o;
      #pragma unroll
      for (int e = 0; e < 4; ++e)
        o[e] = f2bfbits(fmaxf(v[e] + bv4[e], 0.f));
      long oaddr = (long)(oh0 + rr[bf]) * oRS + (long)cc[bf] * oCS + coB;
      *(ushort4v*)(outb + oaddr) = o;
    }
  }
}

// ---------------------------------------------------- VQ via MFMA GEMM
// scores = ssq[k] - 2 * (E . z); per-wave: 64 positions, all 512 codes.
// B-frags (z) loaded once, reused across 32 code-tiles. D layout: col=ln
// (position), row=quad*4+reg (code). In-lane argmin is ascending-k so
// strict < keeps first index; cross-quad reduce tie-breaks on k.
__global__ __launch_bounds__(256) void vq_mfma(
    const bf16* __restrict__ z, long zImgS, int zRowS,
    const bf16* __restrict__ emb, const float* __restrict__ embsq,
    bf16* __restrict__ zq, long qImgS, int qRowS,
    float* __restrict__ loss_acc, int wb, int hwb) {
  const int lane = threadIdx.x & 63, wv = threadIdx.x >> 6;
  const int ln = lane & 15, quad = lane >> 4;
  const int base = blockIdx.x * 256 + wv * 64;

  // load B-frags: 4 position-frags x 4 k-chunks (z stays in regs)
  short8 bfrag[4][4];
  #pragma unroll
  for (int bf = 0; bf < 4; ++bf) {
    int n = base + bf * 16 + ln;
    int b = n >> hwb;
    int rem = n & ((1 << hwb) - 1);
    int y = rem >> wb, x = rem & ((1 << wb) - 1);
    const bf16* zrow = z + (long)b * zImgS + (long)y * zRowS + (long)x * 128;
    #pragma unroll
    for (int kc = 0; kc < 4; ++kc)
      bfrag[bf][kc] = *(const short8*)(zrow + kc * 32 + quad * 8);
  }

  float best0 = 3.4e38f, best1 = 3.4e38f, best2 = 3.4e38f, best3 = 3.4e38f;
  int bk0 = 0, bk1 = 0, bk2 = 0, bk3 = 0;
  for (int ct = 0; ct < 32; ++ct) {
    const bf16* erow = emb + (long)(ct * 16 + ln) * 128 + quad * 8;
    short8 a0 = *(const short8*)(erow);
    short8 a1 = *(const short8*)(erow + 32);
    short8 a2 = *(const short8*)(erow + 64);
    short8 a3 = *(const short8*)(erow + 96);
    float4v sq4 = *(const float4v*)(embsq + ct * 16 + quad * 4);
    #pragma unroll
    for (int bf = 0; bf < 4; ++bf) {
      float4v acc = {0.f, 0.f, 0.f, 0.f};
      acc = __builtin_amdgcn_mfma_f32_16x16x32_bf16(a0, bfrag[bf][0], acc, 0, 0, 0);
      acc = __builtin_amdgcn_mfma_f32_16x16x32_bf16(a1, bfrag[bf][1], acc, 0, 0, 0);
      acc = __builtin_amdgcn_mfma_f32_16x16x32_bf16(a2, bfrag[bf][2], acc, 0, 0, 0);
      acc = __builtin_amdgcn_mfma_f32_16x16x32_bf16(a3, bfrag[bf][3], acc, 0, 0, 0);
      int kb = ct * 16 + quad * 4;
      #pragma unroll
      for (int r = 0; r < 4; ++r) {
        float s = fmaf(-2.f, acc[r], sq4[r]);
        if (bf == 0) { if (s < best0) { best0 = s; bk0 = kb + r; } }
        if (bf == 1) { if (s < best1) { best1 = s; bk1 = kb + r; } }
        if (bf == 2) { if (s < best2) { best2 = s; bk2 = kb + r; } }
        if (bf == 3) { if (s < best3) { best3 = s; bk3 = kb + r; } }
      }
    }
  }
  // cross-quad reduce with first-index tie-break
  float bs[4] = {best0, best1, best2, best3};
  int bk[4] = {bk0, bk1, bk2, bk3};
  #pragma unroll
  for (int bf = 0; bf < 4; ++bf) {
    #pragma unroll
    for (int m = 16; m <= 32; m <<= 1) {
      float os = __shfl_xor(bs[bf], m, 64);
      int ok = __shfl_xor(bk[bf], m, 64);
      if (os < bs[bf] || (os == bs[bf] && ok < bk[bf])) { bs[bf] = os; bk[bf] = ok; }
    }
  }
  // lane handles position of frag index == quad
  int myk = (quad == 0) ? bk[0] : (quad == 1) ? bk[1] : (quad == 2) ? bk[2] : bk[3];
  int n = base + quad * 16 + ln;
  int b = n >> hwb;
  int rem = n & ((1 << hwb) - 1);
  int y = rem >> wb, x = rem & ((1 << wb) - 1);
  const uint4* zr = (const uint4*)(z + (long)b * zImgS + (long)y * zRowS + (long)x * 128);
  uint4* qr = (uint4*)(zq + (long)b * qImgS + (long)y * qRowS + (long)x * 128);
  const uint4* er = (const uint4*)(emb + (long)myk * 128);
  float lsum = 0.f;
  #pragma unroll
  for (int j = 0; j < 16; ++j) {
    uint4 ue = er[j];
    uint4 uz = zr[j];
    qr[j] = ue;
    float ev[8], zv[8];
    unpack_u4(ue, ev);
    unpack_u4(uz, zv);
    #pragma unroll
    for (int e = 0; e < 8; ++e) {
      float dv = ev[e] - zv[e];
      lsum = fmaf(dv, dv, lsum);
    }
  }
  for (int o = 32; o > 0; o >>= 1) lsum += __shfl_down(lsum, o, 64);
  if (lane == 0) atomicAdd(loss_acc, lsum);
}

// ----------------------------------------- final convT(64->3) + sigmoid
__global__ __launch_bounds__(256) void final_convt_sig(
    const bf16* __restrict__ hp, const float* __restrict__ wf,
    const float* __restrict__ bf_, float* __restrict__ out) {
  int tid = blockIdx.x * 256 + threadIdx.x;   // 16*256*256
  int ow = tid & 255; int t = tid >> 8;
  int oh = t & 255; int b = t >> 8;
  int p = oh & 1, y = oh >> 1, q = ow & 1, xx = ow >> 1;
  float a0 = bf_[0], a1 = bf_[1], a2 = bf_[2];
  const bf16* hb = hp + (long)b * 1081600;
  #pragma unroll
  for (int s = 0; s < 2; ++s) {
    #pragma unroll
    for (int t2 = 0; t2 < 2; ++t2) {
      int khkw = (2 * s + 1 - p) * 4 + (2 * t2 + 1 - q);
      const uint4* r4 = (const uint4*)(hb + (long)(y + p - s + 1) * 8320 +
                                       (long)(xx + q - t2 + 1) * 64);
      #pragma unroll
      for (int j = 0; j < 8; ++j) {
        float v[8];
        unpack_u4(r4[j], v);
        #pragma unroll
        for (int e = 0; e < 8; ++e) {
          const float* wc = wf + (j * 8 + e) * 48 + khkw;
          a0 = fmaf(v[e], wc[0], a0);
          a1 = fmaf(v[e], wc[16], a1);
          a2 = fmaf(v[e], wc[32], a2);
        }
      }
    }
  }
  long ob = (long)b * 196608 + (long)oh * 256 + ow;
  out[ob]          = 1.f / (1.f + expf(-a0));
  out[ob + 65536]  = 1.f / (1.f + expf(-a1));
  out[ob + 131072] = 1.f / (1.f + expf(-a2));
}

__global__ void finalize_loss_kernel(const float* __restrict__ lacc, float* __restrict__ out) {
  if (threadIdx.x == 0) {
    float lt = lacc[0] * (1.5f / 2097152.f);
    float lb = lacc[1] * (1.5f / 8388608.f);
    *out = lt + lb;
  }
}

// ------------------------------------------------------------------ launch
extern "C" void kernel_launch(void* const* d_in, const int* in_sizes, int n_in,
                              void* d_out, int out_size, void* d_ws, size_t ws_size,
                              hipStream_t stream) {
  float* out = (float*)d_out;
  char* base = (char*)d_ws;
  size_t off = 0;
  auto alloc = [&](size_t bytes) {
    void* pp = base + off;
    off = (off + bytes + 255) & ~(size_t)255;
    return pp;
  };

  int* flag = (int*)alloc(256);
  float* beB1f = (float*)alloc(64 * 4);
  float* beB2f = (float*)alloc(128 * 4);
  float* beTf  = (float*)alloc(128 * 4);
  float* bdTf  = (float*)alloc(128 * 4);
  float* bd1f  = (float*)alloc(64 * 4);
  float* wd2f  = (float*)alloc(3072 * 4);
  float* bd2f  = (float*)alloc(3 * 4);
  float* sqT   = (float*)alloc(512 * 4);
  float* sqB   = (float*)alloc(512 * 4);
  float* lacc  = (float*)alloc(2 * 4);
  bf16* Wc1  = (bf16*)alloc((size_t)4096 * 2);    // conv1 [64co][64k]
  bf16* Wt2  = (bf16*)alloc((size_t)131072 * 2);
  bf16* Wtt  = (bf16*)alloc((size_t)262144 * 2);
  bf16* Wdt  = (bf16*)alloc((size_t)262144 * 2);
  bf16* Wd1  = (bf16*)alloc((size_t)262144 * 2);
  bf16* embT = (bf16*)alloc((size_t)65536 * 2);
  bf16* embB = (bf16*)alloc((size_t)65536 * 2);
  bf16* colb = (bf16*)alloc((size_t)16777216 * 2);   // im2col [262144][64]
  bf16* act1p = (bf16*)alloc((size_t)17305600 * 2);  // [16][130][130][64]
  bf16* zbp   = (bf16*)alloc((size_t)8921088 * 2);   // [16][66][66][128]
  bf16* zqtp  = (bf16*)alloc((size_t)2367488 * 2);   // [16][34][34][128]
  bf16* eup   = (bf16*)alloc((size_t)8921088 * 2);   // [16][66][66][128]
  bf16* fqp   = (bf16*)alloc((size_t)8921088 * 2);   // [16][66][66][128]
  bf16* hp    = (bf16*)alloc((size_t)17305600 * 2);  // [16][130][130][64]
  bf16* ztp   = (bf16*)alloc((size_t)2097152 * 2);   // [16][32][32][128]

  const long actBytes = ((char*)(ztp + 2097152)) - ((char*)act1p);
  const long n4 = actBytes / 16;

  detect_dtype_kernel<<<1, 256, 0, stream>>>(d_in[0], flag);
  zero_kernel<<<4096, 256, 0, stream>>>((uint4*)act1p, n4);
  zero2_kernel<<<1, 64, 0, stream>>>(lacc);

  // converts / repacks
  rp_c1w<<<16, 256, 0, stream>>>(d_in[1], Wc1, flag);
  conv_f32<<<1, 256, 0, stream>>>(d_in[2], beB1f, 64, flag);
  conv_f32<<<1, 256, 0, stream>>>(d_in[4], beB2f, 128, flag);
  conv_f32<<<1, 256, 0, stream>>>(d_in[6], beTf, 128, flag);
  conv_f32<<<1, 256, 0, stream>>>(d_in[10], bdTf, 128, flag);
  conv_f32<<<1, 256, 0, stream>>>(d_in[12], bd1f, 64, flag);
  conv_f32<<<12, 256, 0, stream>>>(d_in[13], wd2f, 3072, flag);
  conv_f32<<<1, 256, 0, stream>>>(d_in[14], bd2f, 3, flag);
  conv_bf16<<<256, 256, 0, stream>>>(d_in[7], embT, 65536, flag);
  conv_bf16<<<256, 256, 0, stream>>>(d_in[8], embB, 65536, flag);
  embsq_kernel<<<2, 256, 0, stream>>>(embT, sqT);
  embsq_kernel<<<2, 256, 0, stream>>>(embB, sqB);
  rp_conv_w<128, 64><<<512, 256, 0, stream>>>(d_in[3], Wt2, flag);
  rp_conv_w<128, 128><<<1024, 256, 0, stream>>>(d_in[5], Wtt, flag);
  rp_convt_w<128, 128><<<1024, 256, 0, stream>>>(d_in[9], Wdt, flag);
  rp_convt_w<256, 64><<<1024, 256, 0, stream>>>(d_in[11], Wd1, flag);

  // encoder: conv1 = im2col + MFMA GEMM
  im2col1<<<1024, 256, 0, stream>>>(d_in[0], flag, colb);
  gemm1<<<2048, 256, 0, stream>>>(colb, Wc1, beB1f, act1p);
  mfma_conv<128, 64, 64, 2, 16, 64><<<dim3(32, 2, 16), 256, 0, stream>>>(
      act1p, act1p, 1081600, 8320, Wt2, beB2f, zbp + 8576, 557568, 8448, 128, 0);
  mfma_conv<128, 128, 32, 2, 16, 128><<<dim3(8, 2, 16), 256, 0, stream>>>(
      zbp, zbp, 557568, 8448, Wtt, beTf, ztp, 131072, 4096, 128, 0);

  // VQ top (16384 positions)
  vq_mfma<<<64, 256, 0, stream>>>(ztp, 131072, 4096, embT, sqT,
                                  zqtp + 4480, 147968, 4352, lacc + 0, 5, 10);

  // decoder_top upsample: 4 parity classes
  for (int cls = 0; cls < 4; ++cls) {
    int p = cls >> 1, q = cls & 1;
    mfma_conv<128, 128, 32, 1, 4, 128><<<dim3(8, 2, 16), 256, 0, stream>>>(
        zqtp, zqtp, 147968, 4352, Wdt + (long)cls * 65536, bdTf,
        eup + (long)(p + 1) * 8448 + (q + 1) * 128, 557568, 16896, 256, cls);
  }

  // VQ bottom (65536 positions)
  vq_mfma<<<256, 256, 0, stream>>>(zbp + 8576, 557568, 8448, embB, sqB,
                                   fqp + 8576, 557568, 8448, lacc + 1, 6, 12);

  // decoder conv: concat(Fq, Eu) -> h (4 parity classes)
  for (int cls = 0; cls < 4; ++cls) {
    int p = cls >> 1, q = cls & 1;
    mfma_conv<64, 256, 64, 1, 4, 128><<<dim3(32, 1, 16), 256, 0, stream>>>(
        fqp, eup, 557568, 8448, Wd1 + (long)cls * 65536, bd1f,
        hp + (long)(p + 1) * 8320 + (q + 1) * 64, 1081600, 16640, 128, cls);
  }

  // final convT + sigmoid -> fp32 NCHW output
  final_convt_sig<<<4096, 256, 0, stream>>>(hp, wd2f, bd2f, out);
  finalize_loss_kernel<<<1, 64, 0, stream>>>(lacc, out + 3145728);
}

// Round 8
// 747.218 us; speedup vs baseline: 4.3022x; 1.1168x over previous
//
#include <hip/hip_runtime.h>
#include <hip/hip_bf16.h>
#include <cstddef>

typedef __hip_bfloat16 bf16;
typedef __attribute__((ext_vector_type(8))) short short8;
typedef __attribute__((ext_vector_type(4))) float float4v;
typedef __attribute__((ext_vector_type(4))) unsigned short ushort4v;

static __device__ __forceinline__ float b2f(bf16 v) { return __bfloat162float(v); }
static __device__ __forceinline__ float bits2f(unsigned int u) { return __uint_as_float(u); }
static __device__ __forceinline__ unsigned short f2bfbits(float f) {
  bf16 h = __float2bfloat16(f);
  return *reinterpret_cast<unsigned short*>(&h);
}
static __device__ __forceinline__ float ld_any(const void* p, long i, int flag) {
  return flag ? b2f(((const bf16*)p)[i]) : ((const float*)p)[i];
}
static __device__ __forceinline__ void unpack_u4(uint4 u, float* f) {
  f[0] = bits2f(u.x << 16); f[1] = bits2f(u.x & 0xffff0000u);
  f[2] = bits2f(u.y << 16); f[3] = bits2f(u.y & 0xffff0000u);
  f[4] = bits2f(u.z << 16); f[5] = bits2f(u.z & 0xffff0000u);
  f[6] = bits2f(u.w << 16); f[7] = bits2f(u.w & 0xffff0000u);
}

// --------------------------------------------------------- dtype detection
__global__ void detect_dtype_kernel(const void* __restrict__ x, int* __restrict__ flag) {
  __shared__ int ok;
  if (threadIdx.x == 0) ok = 1;
  __syncthreads();
  float v = b2f(((const bf16*)x)[threadIdx.x]);
  if (!(v >= 0.f && v <= 1.0009765625f)) ok = 0;
  __syncthreads();
  if (threadIdx.x == 0) *flag = ok;
}

// ---------------------------------------------------------------- utilities
__global__ void zero_kernel(uint4* __restrict__ p, long n4) {
  long i = (long)blockIdx.x * blockDim.x + threadIdx.x;
  long stride = (long)gridDim.x * blockDim.x;
  uint4 z = {0u, 0u, 0u, 0u};
  for (; i < n4; i += stride) p[i] = z;
}
__global__ void zero2_kernel(float* p) {
  if (threadIdx.x < 2) p[threadIdx.x] = 0.f;
}
__global__ void conv_f32(const void* __restrict__ src, float* __restrict__ dst,
                         int n, const int* __restrict__ flag) {
  int i = blockIdx.x * blockDim.x + threadIdx.x;
  if (i < n) dst[i] = ld_any(src, i, *flag);
}
__global__ void conv_bf16(const void* __restrict__ src, bf16* __restrict__ dst,
                          int n, const int* __restrict__ flag) {
  int i = blockIdx.x * blockDim.x + threadIdx.x;
  if (i >= n) return;
  dst[i] = (*flag) ? ((const bf16*)src)[i] : __float2bfloat16(((const float*)src)[i]);
}
__global__ void embsq_kernel(const bf16* __restrict__ emb, float* __restrict__ out) {
  int k = blockIdx.x * blockDim.x + threadIdx.x;
  if (k >= 512) return;
  float s = 0.f;
  for (int c = 0; c < 128; ++c) { float e = b2f(emb[k * 128 + c]); s = fmaf(e, e, s); }
  out[k] = s;
}

// conv1 weights [64][3][4][4] -> [co][k] bf16, K padded 48->64 with zeros
__global__ void rp_c1w(const void* __restrict__ src, bf16* __restrict__ dst,
                       const int* __restrict__ flag) {
  int i = blockIdx.x * blockDim.x + threadIdx.x;   // 64*64
  if (i >= 4096) return;
  int co = i >> 6, k = i & 63;
  float v = (k < 48) ? ld_any(src, co * 48 + k, *flag) : 0.f;
  dst[i] = __float2bfloat16(v);
}

// weights OIHW [CO][CI][4][4] -> [tap=kh*4+kw][co][ci] bf16
template <int CO, int CI>
__global__ void rp_conv_w(const void* __restrict__ src, bf16* __restrict__ dst,
                          const int* __restrict__ flag) {
  const int N = CO * CI * 16;
  int i = blockIdx.x * blockDim.x + threadIdx.x;
  if (i >= N) return;
  int co = i / (CI * 16);
  int rem = i % (CI * 16);
  int ci = rem >> 4;
  int k = rem & 15;
  dst[((long)k * CO + co) * CI + ci] = __float2bfloat16(ld_any(src, i, *flag));
}

// convT weights [CI][CO][4][4] -> [class pq][tap st][co][ci] bf16
template <int CI, int CO>
__global__ void rp_convt_w(const void* __restrict__ src, bf16* __restrict__ dst,
                           const int* __restrict__ flag) {
  const int N = CI * CO * 16;
  int i = blockIdx.x * blockDim.x + threadIdx.x;
  if (i >= N) return;
  int ci = i / (CO * 16);
  int rem = i % (CO * 16);
  int co = rem >> 4;
  int k = rem & 15;
  int kh = k >> 2, kw = k & 3;
  int p = (kh + 1) & 1, s = (kh - 1 + p) >> 1;
  int q = (kw + 1) & 1, t = (kw - 1 + q) >> 1;
  long d = (((long)(p * 2 + q) * 4 + (s * 2 + t)) * CO + co) * CI + ci;
  dst[d] = __float2bfloat16(ld_any(src, i, *flag));
}

// final convT weights [64ci][3co][4][4] -> A[m=cls*4+co][d=dy*3+dx][64ci]
// (K = 9*64 = 576); zero where tap invalid or co==3.
__global__ void rp_finw(const void* __restrict__ src, bf16* __restrict__ dst,
                        const int* __restrict__ flag) {
  int i = blockIdx.x * blockDim.x + threadIdx.x;   // 16*576 = 9216
  if (i >= 9216) return;
  int m = i / 576, rem = i % 576;
  int d = rem >> 6, ci = rem & 63;
  int cls = m >> 2, co = m & 3;
  int p = cls >> 1, q = cls & 1;
  int dy = d / 3, dx = d % 3;
  int s = p - dy + 1, t = q - dx + 1;
  float v = 0.f;
  if (co < 3 && s >= 0 && s <= 1 && t >= 0 && t <= 1) {
    int kh = 2 * s + 1 - p, kw = 2 * t + 1 - q;
    v = ld_any(src, ci * 48 + co * 16 + kh * 4 + kw, *flag);
  }
  dst[i] = __float2bfloat16(v);
}

// -------------------- conv1 as GEMM: im2col (K padded to 64) + MFMA GEMM
__global__ __launch_bounds__(256) void im2col1(const void* __restrict__ x,
                                               const int* __restrict__ flag,
                                               bf16* __restrict__ col) {
  int tid = blockIdx.x * 256 + threadIdx.x;   // 16*128*128
  int ow = tid & 127; int t = tid >> 7;
  int oh = t & 127; int b = t >> 7;
  int fl = *flag;
  int ih0 = oh * 2 - 1, iw0 = ow * 2 - 1;
  unsigned short vals[64];
  #pragma unroll
  for (int j = 48; j < 64; ++j) vals[j] = 0;
  #pragma unroll
  for (int ci = 0; ci < 3; ++ci) {
    long pbase = ((long)(b * 3 + ci)) << 16;
    #pragma unroll
    for (int kh = 0; kh < 4; ++kh) {
      int ih = ih0 + kh;
      bool okh = (unsigned)ih < 256u;
      long rbase = pbase + ((long)ih << 8);
      #pragma unroll
      for (int kw = 0; kw < 4; ++kw) {
        int iw = iw0 + kw;
        float v = (okh && (unsigned)iw < 256u) ? ld_any(x, rbase + iw, fl) : 0.f;
        vals[ci * 16 + kh * 4 + kw] = f2bfbits(v);
      }
    }
  }
  uint4* dst = (uint4*)(col + (long)tid * 64);
  const uint4* s = (const uint4*)vals;
  #pragma unroll
  for (int j = 0; j < 8; ++j) dst[j] = s[j];
}

// M=64 (co), K=64, N=262144 (positions); bias+relu; store padded NHWC
__global__ __launch_bounds__(256) void gemm1(const bf16* __restrict__ col,
                                             const bf16* __restrict__ w,
                                             const float* __restrict__ bias,
                                             bf16* __restrict__ act1p) {
  const int lane = threadIdx.x & 63, wv = threadIdx.x >> 6;
  const int wm = wv & 1, wn = wv >> 1;
  const int ln = lane & 15, quad = lane >> 4;
  const int n0 = blockIdx.x * 128 + wn * 64;
  float4v acc[2][4];
  #pragma unroll
  for (int i = 0; i < 2; ++i)
    #pragma unroll
    for (int j = 0; j < 4; ++j) acc[i][j] = {0.f, 0.f, 0.f, 0.f};
  #pragma unroll
  for (int kc = 0; kc < 2; ++kc) {
    const bf16* wk = w + (wm * 32 + ln) * 64 + kc * 32 + quad * 8;
    short8 a0 = *(const short8*)(wk);
    short8 a1 = *(const short8*)(wk + 16 * 64);
    #pragma unroll
    for (int bf = 0; bf < 4; ++bf) {
      short8 bv = *(const short8*)(col + (long)(n0 + bf * 16 + ln) * 64 + kc * 32 + quad * 8);
      acc[0][bf] = __builtin_amdgcn_mfma_f32_16x16x32_bf16(a0, bv, acc[0][bf], 0, 0, 0);
      acc[1][bf] = __builtin_amdgcn_mfma_f32_16x16x32_bf16(a1, bv, acc[1][bf], 0, 0, 0);
    }
  }
  #pragma unroll
  for (int mf = 0; mf < 2; ++mf) {
    int coB = wm * 32 + mf * 16 + quad * 4;
    float4v bv4 = *(const float4v*)(bias + coB);
    #pragma unroll
    for (int bf = 0; bf < 4; ++bf) {
      int n = n0 + bf * 16 + ln;
      int ow = n & 127; int t2 = n >> 7;
      int oh = t2 & 127; int b = t2 >> 7;
      long oaddr = ((long)(b * 130 + oh + 1) * 130 + ow + 1) * 64 + coB;
      float4v v = acc[mf][bf];
      ushort4v o;
      #pragma unroll
      for (int e = 0; e < 4; ++e) o[e] = f2bfbits(fmaxf(v[e] + bv4[e], 0.f));
      *(ushort4v*)(act1p + oaddr) = o;
    }
  }
}

// ------------------------------------------- MFMA implicit-GEMM tap conv
template <int COUT, int CINT, int TC, int S, int NT, int INC>
__global__ __launch_bounds__(256) void mfma_conv(
    const bf16* __restrict__ in1, const bf16* __restrict__ in2,
    long inImgS, int inRowS,
    const bf16* __restrict__ w, const float* __restrict__ bias,
    bf16* __restrict__ outp, long outImgS, int oRS, int oCS, int pq) {
  constexpr int TR = 128 / TC;
  constexpr int KC = CINT / 32;
  constexpr int KSPLIT = (CINT > INC) ? (INC / 32) : KC;
  const int lane = threadIdx.x & 63;
  const int wv = threadIdx.x >> 6;
  const int wm = wv & 1, wn = wv >> 1;
  const int ln = lane & 15, quad = lane >> 4;
  const int mTile = blockIdx.y * 64;
  const int oh0 = blockIdx.x * TR;
  const int b = blockIdx.z;
  const int p = pq >> 1, q = pq & 1;

  long posOff[4];
  int rr[4], cc[4];
  #pragma unroll
  for (int bf = 0; bf < 4; ++bf) {
    int n = wn * 64 + bf * 16 + ln;
    int r = n / TC, c = n % TC;
    rr[bf] = r; cc[bf] = c;
    posOff[bf] = (long)(S * (oh0 + r)) * inRowS + (long)(S * c) * INC;
  }
  const bf16* inb1 = in1 + (long)b * inImgS;
  const bf16* inb2 = in2 + (long)b * inImgS;

  float4v acc[2][4];
  #pragma unroll
  for (int i = 0; i < 2; ++i)
    #pragma unroll
    for (int j = 0; j < 4; ++j) acc[i][j] = {0.f, 0.f, 0.f, 0.f};

  for (int t = 0; t < NT; ++t) {
    int dy, dx;
    if (S == 2) { dy = t >> 2; dx = t & 3; }
    else        { dy = p - (t >> 1) + 1; dx = q - (t & 1) + 1; }
    const long tapOff = (long)dy * inRowS + (long)dx * INC;
    const bf16* wt = w + (long)t * COUT * CINT;
    const bf16* wk0 = wt + (long)(mTile + wm * 32 + ln) * CINT + quad * 8;
    #pragma unroll
    for (int kc = 0; kc < KC; ++kc) {
      short8 a0 = *(const short8*)(wk0 + kc * 32);
      short8 a1 = *(const short8*)(wk0 + kc * 32 + 16 * CINT);
      const bf16* bp = (kc < KSPLIT) ? inb1 : inb2;
      int kOff = (kc < KSPLIT ? kc : kc - KSPLIT) * 32 + quad * 8;
      #pragma unroll
      for (int bf = 0; bf < 4; ++bf) {
        short8 bv = *(const short8*)(bp + posOff[bf] + tapOff + kOff);
        acc[0][bf] = __builtin_amdgcn_mfma_f32_16x16x32_bf16(a0, bv, acc[0][bf], 0, 0, 0);
        acc[1][bf] = __builtin_amdgcn_mfma_f32_16x16x32_bf16(a1, bv, acc[1][bf], 0, 0, 0);
      }
    }
  }

  bf16* outb = outp + (long)b * outImgS;
  #pragma unroll
  for (int mf = 0; mf < 2; ++mf) {
    int coB = mTile + wm * 32 + mf * 16 + quad * 4;
    float4v bv4 = *(const float4v*)(bias + coB);
    #pragma unroll
    for (int bf = 0; bf < 4; ++bf) {
      float4v v = acc[mf][bf];
      ushort4v o;
      #pragma unroll
      for (int e = 0; e < 4; ++e)
        o[e] = f2bfbits(fmaxf(v[e] + bv4[e], 0.f));
      long oaddr = (long)(oh0 + rr[bf]) * oRS + (long)cc[bf] * oCS + coB;
      *(ushort4v*)(outb + oaddr) = o;
    }
  }
}

// ---------------------------------------------------- VQ via MFMA GEMM
__global__ __launch_bounds__(256) void vq_mfma(
    const bf16* __restrict__ z, long zImgS, int zRowS,
    const bf16* __restrict__ emb, const float* __restrict__ embsq,
    bf16* __restrict__ zq, long qImgS, int qRowS,
    float* __restrict__ loss_acc, int wb, int hwb) {
  const int lane = threadIdx.x & 63, wv = threadIdx.x >> 6;
  const int ln = lane & 15, quad = lane >> 4;
  const int base = blockIdx.x * 256 + wv * 64;

  short8 bfrag[4][4];
  #pragma unroll
  for (int bf = 0; bf < 4; ++bf) {
    int n = base + bf * 16 + ln;
    int b = n >> hwb;
    int rem = n & ((1 << hwb) - 1);
    int y = rem >> wb, x = rem & ((1 << wb) - 1);
    const bf16* zrow = z + (long)b * zImgS + (long)y * zRowS + (long)x * 128;
    #pragma unroll
    for (int kc = 0; kc < 4; ++kc)
      bfrag[bf][kc] = *(const short8*)(zrow + kc * 32 + quad * 8);
  }

  float best0 = 3.4e38f, best1 = 3.4e38f, best2 = 3.4e38f, best3 = 3.4e38f;
  int bk0 = 0, bk1 = 0, bk2 = 0, bk3 = 0;
  for (int ct = 0; ct < 32; ++ct) {
    const bf16* erow = emb + (long)(ct * 16 + ln) * 128 + quad * 8;
    short8 a0 = *(const short8*)(erow);
    short8 a1 = *(const short8*)(erow + 32);
    short8 a2 = *(const short8*)(erow + 64);
    short8 a3 = *(const short8*)(erow + 96);
    float4v sq4 = *(const float4v*)(embsq + ct * 16 + quad * 4);
    #pragma unroll
    for (int bf = 0; bf < 4; ++bf) {
      float4v acc = {0.f, 0.f, 0.f, 0.f};
      acc = __builtin_amdgcn_mfma_f32_16x16x32_bf16(a0, bfrag[bf][0], acc, 0, 0, 0);
      acc = __builtin_amdgcn_mfma_f32_16x16x32_bf16(a1, bfrag[bf][1], acc, 0, 0, 0);
      acc = __builtin_amdgcn_mfma_f32_16x16x32_bf16(a2, bfrag[bf][2], acc, 0, 0, 0);
      acc = __builtin_amdgcn_mfma_f32_16x16x32_bf16(a3, bfrag[bf][3], acc, 0, 0, 0);
      int kb = ct * 16 + quad * 4;
      #pragma unroll
      for (int r = 0; r < 4; ++r) {
        float s = fmaf(-2.f, acc[r], sq4[r]);
        if (bf == 0) { if (s < best0) { best0 = s; bk0 = kb + r; } }
        if (bf == 1) { if (s < best1) { best1 = s; bk1 = kb + r; } }
        if (bf == 2) { if (s < best2) { best2 = s; bk2 = kb + r; } }
        if (bf == 3) { if (s < best3) { best3 = s; bk3 = kb + r; } }
      }
    }
  }
  float bs[4] = {best0, best1, best2, best3};
  int bk[4] = {bk0, bk1, bk2, bk3};
  #pragma unroll
  for (int bf = 0; bf < 4; ++bf) {
    #pragma unroll
    for (int m = 16; m <= 32; m <<= 1) {
      float os = __shfl_xor(bs[bf], m, 64);
      int ok = __shfl_xor(bk[bf], m, 64);
      if (os < bs[bf] || (os == bs[bf] && ok < bk[bf])) { bs[bf] = os; bk[bf] = ok; }
    }
  }
  int myk = (quad == 0) ? bk[0] : (quad == 1) ? bk[1] : (quad == 2) ? bk[2] : bk[3];
  int n = base + quad * 16 + ln;
  int b = n >> hwb;
  int rem = n & ((1 << hwb) - 1);
  int y = rem >> wb, x = rem & ((1 << wb) - 1);
  const uint4* zr = (const uint4*)(z + (long)b * zImgS + (long)y * zRowS + (long)x * 128);
  uint4* qr = (uint4*)(zq + (long)b * qImgS + (long)y * qRowS + (long)x * 128);
  const uint4* er = (const uint4*)(emb + (long)myk * 128);
  float lsum = 0.f;
  #pragma unroll
  for (int j = 0; j < 16; ++j) {
    uint4 ue = er[j];
    uint4 uz = zr[j];
    qr[j] = ue;
    float ev[8], zv[8];
    unpack_u4(ue, ev);
    unpack_u4(uz, zv);
    #pragma unroll
    for (int e = 0; e < 8; ++e) {
      float dv = ev[e] - zv[e];
      lsum = fmaf(dv, dv, lsum);
    }
  }
  for (int o = 32; o > 0; o >>= 1) lsum += __shfl_down(lsum, o, 64);
  if (lane == 0) atomicAdd(loss_acc, lsum);
}

// --------------------- final convT(64->3)+sigmoid via class-packed MFMA
// A: [m=cls*4+co][k=(dy*3+dx)*64+ci], K=576=18 chunks. B shared across
// classes: B[pos][k] = h[pos+(dy-1,dx-1)][ci]. D: col=ln (pos), row=
// quad*4+reg => quad=class, reg=co.
__global__ __launch_bounds__(256) void final_convt_mfma(
    const bf16* __restrict__ hp, const bf16* __restrict__ wfin,
    const float* __restrict__ bf_, float* __restrict__ out) {
  const int lane = threadIdx.x & 63, wv = threadIdx.x >> 6;
  const int ln = lane & 15, quad = lane >> 4;
  const int base = blockIdx.x * 256 + wv * 64;   // 262144 positions total

  short8 afr[18];
  #pragma unroll
  for (int kc = 0; kc < 18; ++kc)
    afr[kc] = *(const short8*)(wfin + ln * 576 + kc * 32 + quad * 8);

  float4v acc[4];
  #pragma unroll
  for (int bf = 0; bf < 4; ++bf) acc[bf] = {0.f, 0.f, 0.f, 0.f};

  #pragma unroll
  for (int bf = 0; bf < 4; ++bf) {
    int n = base + bf * 16 + ln;
    int xx = n & 127, y = (n >> 7) & 127, b = n >> 14;
    const bf16* hb = hp + (long)b * 1081600 + (long)y * 8320 + (long)xx * 64;
    #pragma unroll
    for (int kc = 0; kc < 18; ++kc) {
      int d = kc >> 1;
      const bf16* bp = hb + (long)(d / 3) * 8320 + (d % 3) * 64 + (kc & 1) * 32 + quad * 8;
      short8 bv = *(const short8*)bp;
      acc[bf] = __builtin_amdgcn_mfma_f32_16x16x32_bf16(afr[kc], bv, acc[bf], 0, 0, 0);
    }
  }

  const int p = quad >> 1, q = quad & 1;
  float b0 = bf_[0], b1 = bf_[1], b2 = bf_[2];
  #pragma unroll
  for (int bf = 0; bf < 4; ++bf) {
    int n = base + bf * 16 + ln;
    int xx = n & 127, y = (n >> 7) & 127, b = n >> 14;
    long ob = (long)b * 196608 + (long)(2 * y + p) * 256 + (2 * xx + q);
    float v0 = acc[bf][0] + b0, v1 = acc[bf][1] + b1, v2 = acc[bf][2] + b2;
    out[ob]          = 1.f / (1.f + expf(-v0));
    out[ob + 65536]  = 1.f / (1.f + expf(-v1));
    out[ob + 131072] = 1.f / (1.f + expf(-v2));
  }
}

__global__ void finalize_loss_kernel(const float* __restrict__ lacc, float* __restrict__ out) {
  if (threadIdx.x == 0) {
    float lt = lacc[0] * (1.5f / 2097152.f);
    float lb = lacc[1] * (1.5f / 8388608.f);
    *out = lt + lb;
  }
}

// ------------------------------------------------------------------ launch
extern "C" void kernel_launch(void* const* d_in, const int* in_sizes, int n_in,
                              void* d_out, int out_size, void* d_ws, size_t ws_size,
                              hipStream_t stream) {
  float* out = (float*)d_out;
  char* base = (char*)d_ws;
  size_t off = 0;
  auto alloc = [&](size_t bytes) {
    void* pp = base + off;
    off = (off + bytes + 255) & ~(size_t)255;
    return pp;
  };

  int* flag = (int*)alloc(256);
  float* beB1f = (float*)alloc(64 * 4);
  float* beB2f = (float*)alloc(128 * 4);
  float* beTf  = (float*)alloc(128 * 4);
  float* bdTf  = (float*)alloc(128 * 4);
  float* bd1f  = (float*)alloc(64 * 4);
  float* bd2f  = (float*)alloc(3 * 4);
  float* sqT   = (float*)alloc(512 * 4);
  float* sqB   = (float*)alloc(512 * 4);
  float* lacc  = (float*)alloc(2 * 4);
  bf16* Wc1  = (bf16*)alloc((size_t)4096 * 2);
  bf16* Wt2  = (bf16*)alloc((size_t)131072 * 2);
  bf16* Wtt  = (bf16*)alloc((size_t)262144 * 2);
  bf16* Wdt  = (bf16*)alloc((size_t)262144 * 2);
  bf16* Wd1  = (bf16*)alloc((size_t)262144 * 2);
  bf16* Wfin = (bf16*)alloc((size_t)9216 * 2);    // [16][576]
  bf16* embT = (bf16*)alloc((size_t)65536 * 2);
  bf16* embB = (bf16*)alloc((size_t)65536 * 2);
  bf16* colb = (bf16*)alloc((size_t)16777216 * 2);   // im2col [262144][64]
  bf16* act1p = (bf16*)alloc((size_t)17305600 * 2);  // [16][130][130][64]
  bf16* zbp   = (bf16*)alloc((size_t)8921088 * 2);   // [16][66][66][128]
  bf16* zqtp  = (bf16*)alloc((size_t)2367488 * 2);   // [16][34][34][128]
  bf16* eup   = (bf16*)alloc((size_t)8921088 * 2);   // [16][66][66][128]
  bf16* fqp   = (bf16*)alloc((size_t)8921088 * 2);   // [16][66][66][128]
  bf16* hp    = (bf16*)alloc((size_t)17305600 * 2);  // [16][130][130][64]
  bf16* ztp   = (bf16*)alloc((size_t)2097152 * 2);   // [16][32][32][128]

  const long actBytes = ((char*)(ztp + 2097152)) - ((char*)act1p);
  const long n4 = actBytes / 16;

  detect_dtype_kernel<<<1, 256, 0, stream>>>(d_in[0], flag);
  zero_kernel<<<4096, 256, 0, stream>>>((uint4*)act1p, n4);
  zero2_kernel<<<1, 64, 0, stream>>>(lacc);

  // converts / repacks
  rp_c1w<<<16, 256, 0, stream>>>(d_in[1], Wc1, flag);
  conv_f32<<<1, 256, 0, stream>>>(d_in[2], beB1f, 64, flag);
  conv_f32<<<1, 256, 0, stream>>>(d_in[4], beB2f, 128, flag);
  conv_f32<<<1, 256, 0, stream>>>(d_in[6], beTf, 128, flag);
  conv_f32<<<1, 256, 0, stream>>>(d_in[10], bdTf, 128, flag);
  conv_f32<<<1, 256, 0, stream>>>(d_in[12], bd1f, 64, flag);
  conv_f32<<<1, 256, 0, stream>>>(d_in[14], bd2f, 3, flag);
  conv_bf16<<<256, 256, 0, stream>>>(d_in[7], embT, 65536, flag);
  conv_bf16<<<256, 256, 0, stream>>>(d_in[8], embB, 65536, flag);
  embsq_kernel<<<2, 256, 0, stream>>>(embT, sqT);
  embsq_kernel<<<2, 256, 0, stream>>>(embB, sqB);
  rp_conv_w<128, 64><<<512, 256, 0, stream>>>(d_in[3], Wt2, flag);
  rp_conv_w<128, 128><<<1024, 256, 0, stream>>>(d_in[5], Wtt, flag);
  rp_convt_w<128, 128><<<1024, 256, 0, stream>>>(d_in[9], Wdt, flag);
  rp_convt_w<256, 64><<<1024, 256, 0, stream>>>(d_in[11], Wd1, flag);
  rp_finw<<<36, 256, 0, stream>>>(d_in[13], Wfin, flag);

  // encoder: conv1 = im2col + MFMA GEMM
  im2col1<<<1024, 256, 0, stream>>>(d_in[0], flag, colb);
  gemm1<<<2048, 256, 0, stream>>>(colb, Wc1, beB1f, act1p);
  mfma_conv<128, 64, 64, 2, 16, 64><<<dim3(32, 2, 16), 256, 0, stream>>>(
      act1p, act1p, 1081600, 8320, Wt2, beB2f, zbp + 8576, 557568, 8448, 128, 0);
  mfma_conv<128, 128, 32, 2, 16, 128><<<dim3(8, 2, 16), 256, 0, stream>>>(
      zbp, zbp, 557568, 8448, Wtt, beTf, ztp, 131072, 4096, 128, 0);

  // VQ top (16384 positions)
  vq_mfma<<<64, 256, 0, stream>>>(ztp, 131072, 4096, embT, sqT,
                                  zqtp + 4480, 147968, 4352, lacc + 0, 5, 10);

  // decoder_top upsample: 4 parity classes
  for (int cls = 0; cls < 4; ++cls) {
    int p = cls >> 1, q = cls & 1;
    mfma_conv<128, 128, 32, 1, 4, 128><<<dim3(8, 2, 16), 256, 0, stream>>>(
        zqtp, zqtp, 147968, 4352, Wdt + (long)cls * 65536, bdTf,
        eup + (long)(p + 1) * 8448 + (q + 1) * 128, 557568, 16896, 256, cls);
  }

  // VQ bottom (65536 positions)
  vq_mfma<<<256, 256, 0, stream>>>(zbp + 8576, 557568, 8448, embB, sqB,
                                   fqp + 8576, 557568, 8448, lacc + 1, 6, 12);

  // decoder conv: concat(Fq, Eu) -> h (4 parity classes)
  for (int cls = 0; cls < 4; ++cls) {
    int p = cls >> 1, q = cls & 1;
    mfma_conv<64, 256, 64, 1, 4, 128><<<dim3(32, 1, 16), 256, 0, stream>>>(
        fqp, eup, 557568, 8448, Wd1 + (long)cls * 65536, bd1f,
        hp + (long)(p + 1) * 8320 + (q + 1) * 64, 1081600, 16640, 128, cls);
  }

  // final convT + sigmoid via MFMA -> fp32 NCHW output
  final_convt_mfma<<<1024, 256, 0, stream>>>(hp, Wfin, bd2f, out);
  finalize_loss_kernel<<<1, 64, 0, stream>>>(lacc, out + 3145728);
}